// Round 11
// baseline (1262.659 us; speedup 1.0000x reference)
//
#include <hip/hip_runtime.h>
#include <math.h>

#define BB 32
#define NN 4096
#define CC 768
#define HH 24
#define HID 3072
#define N2 1536   // 2*C
#define EPSV 1e-6f
#define SCALE 0.17677669529663687f  // 1/sqrt(32)

#define SLICE_S  ((size_t)BB*HH*NN)           // 3,145,728 (one cs score slice)

// workspace offsets (in floats). POOL/MLP/KVB/HBUF contiguous -> single memset.
#define OFF_WF     0                          // 1,179,648
#define OFF_Q      (OFF_WF   + CC*N2)
#define OFF_WQ     (OFF_Q    + BB*CC)         // wqT: [b][c][24]
#define OFF_S      (OFF_WQ   + BB*HH*CC)      // Spart: [2][b][h][n]; slice0 = final S
#define OFF_POOL   (OFF_S    + 2*BB*HH*NN)    // zeroed (atomic accum)
#define OFF_MLP    (OFF_POOL + BB*HH*CC)      // zeroed
#define OFF_KVB    (OFF_MLP  + BB*CC)         // written by wf_gemm epilogue
#define OFF_HBUF   (OFF_KVB  + N2)            // zeroed, [32][6144]
#define OFF_VPART  (OFF_HBUF + BB*2*HID)      // [8][b][768]
#define OFF_OPART  (OFF_VPART+ 8*BB*CC)       // [8][b][768]
#define OFF_LAT2   (OFF_OPART+ 8*BB*CC)
#define OFF_MLPIN  (OFF_LAT2 + BB*CC)
#define ZERO_START OFF_POOL
#define ZERO_FLOATS (BB*HH*CC + BB*CC + N2 + BB*2*HID)

// ---------------------------------------------------------------------------
// Wf = proj_w (768x768) @ kv_w (768x1536).  BM=32 BN=64 BK=32, 2x4 micro-tile.
// Epilogue (m0==0 blocks only): kvb[n] = proj_b . kv_w[:,n] via the staged Bs.
__global__ void wf_gemm(const float* __restrict__ A, const float* __restrict__ Bm,
                        const float* __restrict__ pb, float* __restrict__ Wf,
                        float* __restrict__ kvb) {
    __shared__ float As[32][34];   // [kk][m], transposed
    __shared__ float Bs[32][68];   // [kk][n]
    __shared__ float pbs[768];
    int t = threadIdx.x;
    int tx = t & 15, ty = t >> 4;
    int n0 = blockIdx.x * 64, m0 = blockIdx.y * 32;
    bool doBias = (blockIdx.y == 0);
    if (doBias) for (int i = t; i < 768; i += 256) pbs[i] = pb[i];
    int ar = t >> 3, ak4 = t & 7;
    int bk = t >> 4, bn4 = t & 15;
    const float* Ap  = &A[(size_t)(m0 + ar) * 768 + ak4 * 4];
    const float* Bp0 = &Bm[(size_t)bk * 1536 + n0 + bn4 * 4];
    const float* Bp1 = &Bm[(size_t)(bk + 16) * 1536 + n0 + bn4 * 4];
    float4 a_reg  = *(const float4*)Ap;
    float4 b_reg0 = *(const float4*)Bp0;
    float4 b_reg1 = *(const float4*)Bp1;
    float acc[2][4] = {};
    float bacc[4] = {0.f, 0.f, 0.f, 0.f};
    for (int kt = 0; kt < 24; ++kt) {
        __syncthreads();
        As[ak4 * 4 + 0][ar] = a_reg.x;
        As[ak4 * 4 + 1][ar] = a_reg.y;
        As[ak4 * 4 + 2][ar] = a_reg.z;
        As[ak4 * 4 + 3][ar] = a_reg.w;
        *(float4*)&Bs[bk][bn4 * 4]      = b_reg0;
        *(float4*)&Bs[bk + 16][bn4 * 4] = b_reg1;
        __syncthreads();
        if (kt < 23) {
            int k0 = (kt + 1) * 32;
            a_reg  = *(const float4*)(Ap + k0);
            b_reg0 = *(const float4*)(Bp0 + (size_t)k0 * 1536);
            b_reg1 = *(const float4*)(Bp1 + (size_t)k0 * 1536);
        }
        #pragma unroll
        for (int kk = 0; kk < 32; ++kk) {
            float a0 = As[kk][ty * 2], a1 = As[kk][ty * 2 + 1];
            float4 bv = *(const float4*)&Bs[kk][tx * 4];
            acc[0][0] += a0 * bv.x; acc[0][1] += a0 * bv.y;
            acc[0][2] += a0 * bv.z; acc[0][3] += a0 * bv.w;
            acc[1][0] += a1 * bv.x; acc[1][1] += a1 * bv.y;
            acc[1][2] += a1 * bv.z; acc[1][3] += a1 * bv.w;
        }
        if (doBias && ty == 0) {
            int kbase = kt * 32;
            #pragma unroll
            for (int kk = 0; kk < 32; ++kk) {
                float p = pbs[kbase + kk];
                float4 bv = *(const float4*)&Bs[kk][tx * 4];
                bacc[0] += p * bv.x; bacc[1] += p * bv.y;
                bacc[2] += p * bv.z; bacc[3] += p * bv.w;
            }
        }
    }
    #pragma unroll
    for (int i = 0; i < 2; ++i) {
        int m = m0 + ty * 2 + i;
        *(float4*)&Wf[(size_t)m * 1536 + n0 + tx * 4] =
            make_float4(acc[i][0], acc[i][1], acc[i][2], acc[i][3]);
    }
    if (doBias && ty == 0)
        *(float4*)&kvb[n0 + tx * 4] = make_float4(bacc[0], bacc[1], bacc[2], bacc[3]);
}

// q[b,:] = (latents + emb[b]) @ q_w
__global__ void q_k(const float* __restrict__ latents, const float* __restrict__ emb,
                    const float* __restrict__ qw, float* __restrict__ q) {
    __shared__ float Ls[768];
    int b = blockIdx.y, t = threadIdx.x;
    for (int i = t; i < 768; i += 256) Ls[i] = latents[i] + emb[b * 768 + i];
    __syncthreads();
    int j = blockIdx.x * 256 + t;
    float acc = 0.f;
    for (int c = 0; c < 768; ++c) acc += Ls[c] * qw[c * 768 + j];
    q[b * 768 + j] = acc;
}

// wqT[b,c,h] = scale * sum_d Wf[c, h*32+d] * q[b,h*32+d]
__global__ void wq_k(const float* __restrict__ Wf, const float* __restrict__ q,
                     float* __restrict__ wqT) {
    int h = blockIdx.x, b = blockIdx.y, t = threadIdx.x;
    __shared__ float qh[32];
    if (t < 32) qh[t] = q[b * 768 + h * 32 + t];
    __syncthreads();
    for (int c = t; c < 768; c += 256) {
        const float4* wrow = (const float4*)&Wf[(size_t)c * 1536 + h * 32];
        float acc = 0.f;
        #pragma unroll
        for (int d4 = 0; d4 < 8; ++d4) {
            float4 w = wrow[d4];
            acc += w.x * qh[4*d4] + w.y * qh[4*d4+1] + w.z * qh[4*d4+2] + w.w * qh[4*d4+3];
        }
        wqT[((size_t)b * 768 + c) * 24 + h] = SCALE * acc;
    }
}

// Spart[cs][b][h][n] = x[b,n,cs-range] . wqT[b,cs-range,h]    (pass 1 over x)
// Wave-private LDS staging (NO barriers): each wave owns 64 rows + 8.25KB LDS.
__global__ void scores_k(const float* __restrict__ x, const float* __restrict__ wqT,
                         float* __restrict__ Spart) {
    __shared__ float Xs[4][64][33];
    int b = blockIdx.z, cs = blockIdx.y;
    int t = threadIdx.x;
    int w = t >> 6, lane = t & 63;
    int n0 = blockIdx.x * 256 + w * 64;
    int sr = lane >> 3, sc = (lane & 7) * 4;   // staging: 8 rows x 32 floats
    const float* __restrict__ xbase = &x[((size_t)b * 4096 + n0) * 768 + cs * 384];
    const float* __restrict__ wb = &wqT[((size_t)b * 768 + cs * 384) * 24];
    float (*Xw)[33] = Xs[w];
    float acc[24];
    #pragma unroll
    for (int h = 0; h < 24; ++h) acc[h] = 0.f;
    float4 pf[8];
    #pragma unroll
    for (int it = 0; it < 8; ++it)
        pf[it] = *(const float4*)&xbase[(size_t)(sr + 8 * it) * 768 + sc];
    for (int ck = 0; ck < 12; ++ck) {
        #pragma unroll
        for (int it = 0; it < 8; ++it) {
            int r = sr + 8 * it;
            Xw[r][sc + 0] = pf[it].x; Xw[r][sc + 1] = pf[it].y;
            Xw[r][sc + 2] = pf[it].z; Xw[r][sc + 3] = pf[it].w;
        }
        if (ck < 11) {
            #pragma unroll
            for (int it = 0; it < 8; ++it)
                pf[it] = *(const float4*)&xbase[(size_t)(sr + 8 * it) * 768 + (ck + 1) * 32 + sc];
        }
        const float* __restrict__ wc = &wb[ck * 32 * 24];
        #pragma unroll
        for (int cc = 0; cc < 32; ++cc) {
            float xv = Xw[lane][cc];
            #pragma unroll
            for (int h = 0; h < 24; ++h)
                acc[h] += xv * wc[cc * 24 + h];          // uniform -> s_load
        }
    }
    int n = n0 + lane;
    #pragma unroll
    for (int h = 0; h < 24; ++h)
        Spart[((size_t)(cs * 32 + b) * 24 + h) * 4096 + n] = acc[h];
}

// softmax over n: S = softmax(p0 + p1); writes into slice 0 (final S)
__global__ void softmax_k(float* __restrict__ Sp) {
    int row = blockIdx.x;            // b*24 + h
    int t = threadIdx.x;
    size_t base = (size_t)row * 4096;
    float v[16];
    float m = -1e30f;
    #pragma unroll
    for (int i = 0; i < 16; ++i) {
        int idx = t + 256 * i;
        v[i] = Sp[base + idx] + Sp[SLICE_S + base + idx];
        m = fmaxf(m, v[i]);
    }
    __shared__ float redm[4];
    for (int off = 32; off > 0; off >>= 1) m = fmaxf(m, __shfl_down(m, off));
    if ((t & 63) == 0) redm[t >> 6] = m;
    __syncthreads();
    m = fmaxf(fmaxf(redm[0], redm[1]), fmaxf(redm[2], redm[3]));
    float s = 0.f;
    #pragma unroll
    for (int i = 0; i < 16; ++i) { v[i] = __expf(v[i] - m); s += v[i]; }
    __shared__ float reds[4];
    for (int off = 32; off > 0; off >>= 1) s += __shfl_down(s, off);
    if ((t & 63) == 0) reds[t >> 6] = s;
    __syncthreads();
    s = reds[0] + reds[1] + reds[2] + reds[3];
    float inv = 1.0f / s;
    #pragma unroll
    for (int i = 0; i < 16; ++i) Sp[base + t + 256 * i] = v[i] * inv;
}

// pool[b,h,c] += sum_{n in chunk} S[b,h,n] * x[b,n,c]   (pass 2 over x)
// Inner loop identical to the proven no-spill version; atomic epilogue.
__global__ void pooled_k(const float* __restrict__ x, const float* __restrict__ S,
                         float* __restrict__ pool) {
    int nt = blockIdx.x, b = blockIdx.y;
    int t = threadIdx.x;          // 0..191
    int c = t * 4;
    int n0 = nt * 128;
    const float* __restrict__ Sb = &S[(size_t)b * 24 * 4096 + n0];
    const float* __restrict__ xb = &x[((size_t)b * 4096 + n0) * 768 + c];
    float ax[24], ay[24], az[24], aw[24];
    #pragma unroll
    for (int h = 0; h < 24; ++h) { ax[h]=0.f; ay[h]=0.f; az[h]=0.f; aw[h]=0.f; }
    #pragma unroll 4
    for (int i = 0; i < 128; ++i) {
        float4 xv = *(const float4*)&xb[(size_t)i * 768];
        #pragma unroll
        for (int h = 0; h < 24; ++h) {
            float s = Sb[h * 4096 + i];          // uniform -> s_load
            ax[h] += s * xv.x; ay[h] += s * xv.y;
            az[h] += s * xv.z; aw[h] += s * xv.w;
        }
    }
    float* dst = &pool[(size_t)b * 24 * 768];
    #pragma unroll
    for (int h = 0; h < 24; ++h) {
        atomicAdd(&dst[h * 768 + c + 0], ax[h]);
        atomicAdd(&dst[h * 768 + c + 1], ay[h]);
        atomicAdd(&dst[h * 768 + c + 2], az[h]);
        atomicAdd(&dst[h * 768 + c + 3], aw[h]);
    }
}

// vpart[cs][b][j] = sum_{c in 96-range} pool[b,h(j),c] * Wf[c,768+j]
__global__ void vals_k(const float* __restrict__ pool, const float* __restrict__ Wf,
                       float* __restrict__ vpart) {
    __shared__ float Ls[24][96];
    int b = blockIdx.x, cs = blockIdx.y, t = threadIdx.x;   // block = 768
    int c0 = cs * 96;
    for (int idx = t; idx < 24 * 96; idx += 768) {
        int hh = idx / 96, cc = idx % 96;
        Ls[hh][cc] = pool[((size_t)b * 24 + hh) * 768 + c0 + cc];
    }
    __syncthreads();
    int h = t >> 5;
    float acc = 0.f;
    for (int cc = 0; cc < 96; ++cc)
        acc += Ls[h][cc] * Wf[(size_t)(c0 + cc) * 1536 + 768 + t];
    vpart[((size_t)cs * 32 + b) * 768 + t] = acc;
}

// opart[cs][b][j] = sum_{c in 96-range} vals[b,c] * ow[c,j]
// vals[b,c] = kvb_V[c] + sum_cs' vpart (summed inline in LDS stage)
__global__ void oproj_k(const float* __restrict__ vpart, const float* __restrict__ kvb,
                        const float* __restrict__ ow, float* __restrict__ opart) {
    __shared__ float Vs[96];
    int b = blockIdx.x, cs = blockIdx.y, t = threadIdx.x;   // block = 768
    int c0 = cs * 96;
    if (t < 96) {
        float v = kvb[768 + c0 + t];
        #pragma unroll
        for (int s2 = 0; s2 < 8; ++s2) v += vpart[((size_t)s2 * 32 + b) * 768 + c0 + t];
        Vs[t] = v;
    }
    __syncthreads();
    float acc = 0.f;
    for (int cc = 0; cc < 96; ++cc)
        acc += Vs[cc] * ow[(size_t)(c0 + cc) * 768 + t];
    opart[((size_t)cs * 32 + b) * 768 + t] = acc;
}

// attn finish: y = latents+emb+ob+sum_cs opart; RMSNorm -> lat2
__global__ void attnfin_k(const float* __restrict__ opart, const float* __restrict__ ob,
                          const float* __restrict__ latents, const float* __restrict__ emb,
                          const float* __restrict__ nw, float* __restrict__ lat2) {
    int b = blockIdx.x, t = threadIdx.x;   // 768
    float y = latents[t] + emb[b * 768 + t] + ob[t];
    #pragma unroll
    for (int cs = 0; cs < 8; ++cs) y += opart[((size_t)cs * 32 + b) * 768 + t];
    float s = y * y;
    for (int off = 32; off > 0; off >>= 1) s += __shfl_down(s, off);
    __shared__ float red[12];
    if ((t & 63) == 0) red[t >> 6] = s;
    __syncthreads();
    float tot = 0.f;
    #pragma unroll
    for (int w = 0; w < 12; ++w) tot += red[w];
    float rstd = rsqrtf(tot / 768.0f + EPSV);
    lat2[b * 768 + t] = y * rstd * nw[t];
}

// GLU pre-activation partials: hbuf[b][j(P)], hbuf[b][3072+j(G)] += lat2-chunk @ gw
__global__ void glu_k(const float* __restrict__ lat2, const float* __restrict__ gw,
                      const float* __restrict__ gb, float* __restrict__ hbuf) {
    int jt = blockIdx.x, bg = blockIdx.y, cs = blockIdx.z, t = threadIdx.x;
    int j = jt * 256 + t;   // < 3072
    float accP[4] = {0.f,0.f,0.f,0.f}, accG[4] = {0.f,0.f,0.f,0.f};
    if (cs == 0) {
        float bp = gb[j], bgv = gb[j + 3072];
        #pragma unroll
        for (int bb = 0; bb < 4; ++bb) { accP[bb] = bp; accG[bb] = bgv; }
    }
    const float* __restrict__ l2 = &lat2[(size_t)(bg * 4) * 768 + cs * 256];
    for (int c = 0; c < 256; ++c) {
        float wp = gw[(size_t)(cs * 256 + c) * 6144 + j];
        float wg = gw[(size_t)(cs * 256 + c) * 6144 + 3072 + j];
        #pragma unroll
        for (int bb = 0; bb < 4; ++bb) {
            float lv = l2[bb * 768 + c];         // uniform -> s_load
            accP[bb] += lv * wp;
            accG[bb] += lv * wg;
        }
    }
    #pragma unroll
    for (int bb = 0; bb < 4; ++bb) {
        atomicAdd(&hbuf[(size_t)(bg * 4 + bb) * 6144 + j],        accP[bb]);
        atomicAdd(&hbuf[(size_t)(bg * 4 + bb) * 6144 + 3072 + j], accG[bb]);
    }
}

// silu finish: mlpin[b][j] = P * silu(G)
__global__ void gfin_k(const float* __restrict__ hbuf, float* __restrict__ mlpin) {
    int idx = blockIdx.x * 256 + threadIdx.x;   // < 98304
    int b = idx / 3072, j = idx % 3072;
    float P = hbuf[(size_t)b * 6144 + j];
    float G = hbuf[(size_t)b * 6144 + 3072 + j];
    mlpin[idx] = P * (G / (1.0f + __expf(-G)));
}

// mlp[b,j] += mlp_in[b, i-chunk] @ mlp_out_w[i-chunk, j]  (+bias once; pre-zeroed)
__global__ void mlpout_k(const float* __restrict__ mlpin, const float* __restrict__ mw,
                         const float* __restrict__ mb, float* __restrict__ mlp) {
    int jt = blockIdx.x, bg = blockIdx.y, ic = blockIdx.z, t = threadIdx.x;
    int j = jt * 256 + t;   // < 768
    int i0 = ic * 384;
    const float* __restrict__ mi = &mlpin[(size_t)(bg * 4) * 3072 + i0];
    float acc[4] = {0.f, 0.f, 0.f, 0.f};
    for (int i = 0; i < 384; ++i) {
        float w = mw[(size_t)(i0 + i) * 768 + j];
        #pragma unroll
        for (int bb = 0; bb < 4; ++bb)
            acc[bb] += mi[bb * 3072 + i] * w;    // uniform -> s_load
    }
    float bias = (ic == 0) ? mb[j] : 0.f;
    #pragma unroll
    for (int bb = 0; bb < 4; ++bb)
        atomicAdd(&mlp[(bg * 4 + bb) * 768 + j], acc[bb] + bias);
}

// final residual + RMSNorm -> out
__global__ void fnorm_k(const float* __restrict__ lat2, const float* __restrict__ mlp,
                        const float* __restrict__ nw, float* __restrict__ out) {
    int b = blockIdx.x, t = threadIdx.x;   // block = 768
    float y = lat2[b * 768 + t] + mlp[b * 768 + t];
    float s = y * y;
    for (int off = 32; off > 0; off >>= 1) s += __shfl_down(s, off);
    __shared__ float red[12];
    if ((t & 63) == 0) red[t >> 6] = s;
    __syncthreads();
    float tot = 0.f;
    #pragma unroll
    for (int w = 0; w < 12; ++w) tot += red[w];
    float rstd = rsqrtf(tot / 768.0f + EPSV);
    out[b * 768 + t] = y * rstd * nw[t];
}

extern "C" void kernel_launch(void* const* d_in, const int* in_sizes, int n_in,
                              void* d_out, int out_size, void* d_ws, size_t ws_size,
                              hipStream_t stream) {
    const float* x       = (const float*)d_in[0];
    const float* emb     = (const float*)d_in[1];
    const float* latents = (const float*)d_in[2];
    const float* proj_w  = (const float*)d_in[3];
    const float* proj_b  = (const float*)d_in[4];
    const float* q_w     = (const float*)d_in[5];
    const float* kv_w    = (const float*)d_in[6];
    const float* ao_w    = (const float*)d_in[7];
    const float* ao_b    = (const float*)d_in[8];
    const float* anw     = (const float*)d_in[9];
    const float* mnw     = (const float*)d_in[10];
    const float* glu_w   = (const float*)d_in[11];
    const float* glu_b   = (const float*)d_in[12];
    const float* mo_w    = (const float*)d_in[13];
    const float* mo_b    = (const float*)d_in[14];

    float* ws    = (float*)d_ws;
    float* Wf    = ws + OFF_WF;
    float* q     = ws + OFF_Q;
    float* wqT   = ws + OFF_WQ;
    float* Sp    = ws + OFF_S;
    float* pool  = ws + OFF_POOL;
    float* mlp   = ws + OFF_MLP;
    float* kvb   = ws + OFF_KVB;
    float* hbuf  = ws + OFF_HBUF;
    float* vpart = ws + OFF_VPART;
    float* opart = ws + OFF_OPART;
    float* lat2  = ws + OFF_LAT2;
    float* mlpin = ws + OFF_MLPIN;

    // zero pool + mlp + kvb + hbuf (contiguous) for atomic accumulation
    hipMemsetAsync(ws + ZERO_START, 0, (size_t)ZERO_FLOATS * sizeof(float), stream);

    wf_gemm<<<dim3(24, 24), 256, 0, stream>>>(proj_w, kv_w, proj_b, Wf, kvb);
    q_k<<<dim3(3, 32), 256, 0, stream>>>(latents, emb, q_w, q);
    wq_k<<<dim3(24, 32), 256, 0, stream>>>(Wf, q, wqT);

    scores_k<<<dim3(16, 2, 32), 256, 0, stream>>>(x, wqT, Sp);
    softmax_k<<<dim3(768), 256, 0, stream>>>(Sp);
    pooled_k<<<dim3(32, 32), 192, 0, stream>>>(x, Sp, pool);

    vals_k<<<dim3(32, 8), 768, 0, stream>>>(pool, Wf, vpart);
    oproj_k<<<dim3(32, 8), 768, 0, stream>>>(vpart, kvb, ao_w, opart);
    attnfin_k<<<dim3(32), 768, 0, stream>>>(opart, ao_b, latents, emb, anw, lat2);

    glu_k<<<dim3(12, 8, 3), 256, 0, stream>>>(lat2, glu_w, glu_b, hbuf);
    gfin_k<<<dim3(384), 256, 0, stream>>>(hbuf, mlpin);
    mlpout_k<<<dim3(3, 8, 8), 256, 0, stream>>>(mlpin, mo_w, mo_b, mlp);
    fnorm_k<<<dim3(32), 768, 0, stream>>>(lat2, mlp, mnw, (float*)d_out);
}

// Round 12
// 458.972 us; speedup vs baseline: 2.7511x; 2.7511x over previous
//
#include <hip/hip_runtime.h>
#include <math.h>

#define BB 32
#define NN 4096
#define CC 768
#define HH 24
#define HID 3072
#define N2 1536   // 2*C
#define EPSV 1e-6f
#define SCALE 0.17677669529663687f  // 1/sqrt(32)

#define SLICE_S  ((size_t)BB*HH*NN)           // 3,145,728 (one cs score slice)
#define SLICE_P  ((size_t)BB*HH*CC)           // 589,824

// workspace offsets (in floats). MLP/KVB/HBUF contiguous -> single memset.
#define OFF_WF     0                          // 1,179,648
#define OFF_Q      (OFF_WF   + CC*N2)
#define OFF_WQ     (OFF_Q    + BB*CC)         // wqT: [b][c][24]
#define OFF_S      (OFF_WQ   + BB*HH*CC)      // Spart: [2][b][h][n]; slice0 = final S
#define OFF_PPART  (OFF_S    + 2*BB*HH*NN)    // [32][b][h][c]
#define OFF_POOL   (OFF_PPART+ 32*BB*HH*CC)
#define OFF_MLP    (OFF_POOL + BB*HH*CC)      // zeroed
#define OFF_KVB    (OFF_MLP  + BB*CC)         // zeroed
#define OFF_HBUF   (OFF_KVB  + N2)            // zeroed, [32][6144]
#define OFF_VPART  (OFF_HBUF + BB*2*HID)      // [8][b][768]
#define OFF_OPART  (OFF_VPART+ 8*BB*CC)       // [8][b][768]
#define OFF_LAT2   (OFF_OPART+ 8*BB*CC)
#define OFF_MLPIN  (OFF_LAT2 + BB*CC)
#define ZERO_START OFF_MLP
#define ZERO_FLOATS (BB*CC + N2 + BB*2*HID)

// ---------------------------------------------------------------------------
// Wf = proj_w (768x768) @ kv_w (768x1536).  BM=32 BN=64 BK=32, 2x4 micro-tile.
__global__ void wf_gemm(const float* __restrict__ A, const float* __restrict__ Bm,
                        float* __restrict__ Wf) {
    __shared__ float As[32][34];   // [kk][m], transposed
    __shared__ float Bs[32][68];   // [kk][n]
    int t = threadIdx.x;
    int tx = t & 15, ty = t >> 4;
    int n0 = blockIdx.x * 64, m0 = blockIdx.y * 32;
    int ar = t >> 3, ak4 = t & 7;
    int bk = t >> 4, bn4 = t & 15;
    const float* Ap  = &A[(size_t)(m0 + ar) * 768 + ak4 * 4];
    const float* Bp0 = &Bm[(size_t)bk * 1536 + n0 + bn4 * 4];
    const float* Bp1 = &Bm[(size_t)(bk + 16) * 1536 + n0 + bn4 * 4];
    float4 a_reg  = *(const float4*)Ap;
    float4 b_reg0 = *(const float4*)Bp0;
    float4 b_reg1 = *(const float4*)Bp1;
    float acc[2][4] = {};
    for (int kt = 0; kt < 24; ++kt) {
        __syncthreads();
        As[ak4 * 4 + 0][ar] = a_reg.x;
        As[ak4 * 4 + 1][ar] = a_reg.y;
        As[ak4 * 4 + 2][ar] = a_reg.z;
        As[ak4 * 4 + 3][ar] = a_reg.w;
        *(float4*)&Bs[bk][bn4 * 4]      = b_reg0;
        *(float4*)&Bs[bk + 16][bn4 * 4] = b_reg1;
        __syncthreads();
        if (kt < 23) {
            int k0 = (kt + 1) * 32;
            a_reg  = *(const float4*)(Ap + k0);
            b_reg0 = *(const float4*)(Bp0 + (size_t)k0 * 1536);
            b_reg1 = *(const float4*)(Bp1 + (size_t)k0 * 1536);
        }
        #pragma unroll
        for (int kk = 0; kk < 32; ++kk) {
            float a0 = As[kk][ty * 2], a1 = As[kk][ty * 2 + 1];
            float4 bv = *(const float4*)&Bs[kk][tx * 4];
            acc[0][0] += a0 * bv.x; acc[0][1] += a0 * bv.y;
            acc[0][2] += a0 * bv.z; acc[0][3] += a0 * bv.w;
            acc[1][0] += a1 * bv.x; acc[1][1] += a1 * bv.y;
            acc[1][2] += a1 * bv.z; acc[1][3] += a1 * bv.w;
        }
    }
    #pragma unroll
    for (int i = 0; i < 2; ++i) {
        int m = m0 + ty * 2 + i;
        *(float4*)&Wf[(size_t)m * 1536 + n0 + tx * 4] =
            make_float4(acc[i][0], acc[i][1], acc[i][2], acc[i][3]);
    }
}

// V-half bias only (K bias is constant over n -> cancels in softmax)
__global__ void kvbias_k(const float* __restrict__ pb, const float* __restrict__ kvw,
                         float* __restrict__ kvb) {
    int j = 768 + blockIdx.x * 256 + threadIdx.x;
    int i0 = blockIdx.y * 192;
    float acc = 0.f;
    for (int i = i0; i < i0 + 192; ++i) acc += pb[i] * kvw[(size_t)i * 1536 + j];
    atomicAdd(&kvb[j], acc);
}

// q[b,:] = (latents + emb[b]) @ q_w
__global__ void q_k(const float* __restrict__ latents, const float* __restrict__ emb,
                    const float* __restrict__ qw, float* __restrict__ q) {
    __shared__ float Ls[768];
    int b = blockIdx.y, t = threadIdx.x;
    for (int i = t; i < 768; i += 256) Ls[i] = latents[i] + emb[b * 768 + i];
    __syncthreads();
    int j = blockIdx.x * 256 + t;
    float acc = 0.f;
    for (int c = 0; c < 768; ++c) acc += Ls[c] * qw[c * 768 + j];
    q[b * 768 + j] = acc;
}

// wqT[b,c,h] = scale * sum_d Wf[c, h*32+d] * q[b,h*32+d]
__global__ void wq_k(const float* __restrict__ Wf, const float* __restrict__ q,
                     float* __restrict__ wqT) {
    int h = blockIdx.x, b = blockIdx.y, t = threadIdx.x;
    __shared__ float qh[32];
    if (t < 32) qh[t] = q[b * 768 + h * 32 + t];
    __syncthreads();
    for (int c = t; c < 768; c += 256) {
        const float4* wrow = (const float4*)&Wf[(size_t)c * 1536 + h * 32];
        float acc = 0.f;
        #pragma unroll
        for (int d4 = 0; d4 < 8; ++d4) {
            float4 w = wrow[d4];
            acc += w.x * qh[4*d4] + w.y * qh[4*d4+1] + w.z * qh[4*d4+2] + w.w * qh[4*d4+3];
        }
        wqT[((size_t)b * 768 + c) * 24 + h] = SCALE * acc;
    }
}

// Spart[cs][b][h][n] = x[b,n,cs-range] . wqT[b,cs-range,h]    (pass 1 over x)
// Wave-private LDS staging (NO barriers): each wave owns 64 rows + 8.25KB LDS.
__global__ void scores_k(const float* __restrict__ x, const float* __restrict__ wqT,
                         float* __restrict__ Spart) {
    __shared__ float Xs[4][64][33];
    int b = blockIdx.z, cs = blockIdx.y;
    int t = threadIdx.x;
    int w = t >> 6, lane = t & 63;
    int n0 = blockIdx.x * 256 + w * 64;
    int sr = lane >> 3, sc = (lane & 7) * 4;   // staging: 8 rows x 32 floats
    const float* __restrict__ xbase = &x[((size_t)b * 4096 + n0) * 768 + cs * 384];
    const float* __restrict__ wb = &wqT[((size_t)b * 768 + cs * 384) * 24];
    float (*Xw)[33] = Xs[w];
    float acc[24];
    #pragma unroll
    for (int h = 0; h < 24; ++h) acc[h] = 0.f;
    float4 pf[8];
    #pragma unroll
    for (int it = 0; it < 8; ++it)
        pf[it] = *(const float4*)&xbase[(size_t)(sr + 8 * it) * 768 + sc];
    for (int ck = 0; ck < 12; ++ck) {
        #pragma unroll
        for (int it = 0; it < 8; ++it) {
            int r = sr + 8 * it;
            Xw[r][sc + 0] = pf[it].x; Xw[r][sc + 1] = pf[it].y;
            Xw[r][sc + 2] = pf[it].z; Xw[r][sc + 3] = pf[it].w;
        }
        if (ck < 11) {
            #pragma unroll
            for (int it = 0; it < 8; ++it)
                pf[it] = *(const float4*)&xbase[(size_t)(sr + 8 * it) * 768 + (ck + 1) * 32 + sc];
        }
        const float* __restrict__ wc = &wb[ck * 32 * 24];
        #pragma unroll
        for (int cc = 0; cc < 32; ++cc) {
            float xv = Xw[lane][cc];
            #pragma unroll
            for (int h = 0; h < 24; ++h)
                acc[h] += xv * wc[cc * 24 + h];          // uniform -> s_load
        }
    }
    int n = n0 + lane;
    #pragma unroll
    for (int h = 0; h < 24; ++h)
        Spart[((size_t)(cs * 32 + b) * 24 + h) * 4096 + n] = acc[h];
}

// softmax over n: S = softmax(p0 + p1); writes into slice 0 (final S)
__global__ void softmax_k(float* __restrict__ Sp) {
    int row = blockIdx.x;            // b*24 + h
    int t = threadIdx.x;
    size_t base = (size_t)row * 4096;
    float v[16];
    float m = -1e30f;
    #pragma unroll
    for (int i = 0; i < 16; ++i) {
        int idx = t + 256 * i;
        v[i] = Sp[base + idx] + Sp[SLICE_S + base + idx];
        m = fmaxf(m, v[i]);
    }
    __shared__ float redm[4];
    for (int off = 32; off > 0; off >>= 1) m = fmaxf(m, __shfl_down(m, off));
    if ((t & 63) == 0) redm[t >> 6] = m;
    __syncthreads();
    m = fmaxf(fmaxf(redm[0], redm[1]), fmaxf(redm[2], redm[3]));
    float s = 0.f;
    #pragma unroll
    for (int i = 0; i < 16; ++i) { v[i] = __expf(v[i] - m); s += v[i]; }
    __shared__ float reds[4];
    for (int off = 32; off > 0; off >>= 1) s += __shfl_down(s, off);
    if ((t & 63) == 0) reds[t >> 6] = s;
    __syncthreads();
    s = reds[0] + reds[1] + reds[2] + reds[3];
    float inv = 1.0f / s;
    #pragma unroll
    for (int i = 0; i < 16; ++i) Sp[base + t + 256 * i] = v[i] * inv;
}

// ppart[nt][b][h][c] = sum_{n in chunk} S[b,h,n] * x[b,n,c]   (pass 2 over x)
// K10-exact: weights via wave-uniform s_load; 96 VGPR accs; coalesced stores.
__global__ void pooled_k(const float* __restrict__ x, const float* __restrict__ S,
                         float* __restrict__ ppart) {
    int nt = blockIdx.x, b = blockIdx.y;
    int t = threadIdx.x;          // 0..191
    int c = t * 4;
    int n0 = nt * 128;
    const float* __restrict__ Sb = &S[(size_t)b * 24 * 4096 + n0];
    const float* __restrict__ xb = &x[((size_t)b * 4096 + n0) * 768 + c];
    float ax[24], ay[24], az[24], aw[24];
    #pragma unroll
    for (int h = 0; h < 24; ++h) { ax[h]=0.f; ay[h]=0.f; az[h]=0.f; aw[h]=0.f; }
    #pragma unroll 4
    for (int i = 0; i < 128; ++i) {
        float4 xv = *(const float4*)&xb[(size_t)i * 768];
        #pragma unroll
        for (int h = 0; h < 24; ++h) {
            float s = Sb[h * 4096 + i];          // uniform -> s_load
            ax[h] += s * xv.x; ay[h] += s * xv.y;
            az[h] += s * xv.z; aw[h] += s * xv.w;
        }
    }
    float* dst = &ppart[(size_t)(nt * 32 + b) * 24 * 768];
    #pragma unroll
    for (int h = 0; h < 24; ++h)
        *(float4*)&dst[h * 768 + c] = make_float4(ax[h], ay[h], az[h], aw[h]);
}

// pool[i] = sum over 32 slices of ppart
__global__ void reduce_k(const float* __restrict__ ppart, float* __restrict__ pool) {
    size_t base = ((size_t)blockIdx.x * 256 + threadIdx.x) * 4;
    float sx=0.f, sy=0.f, sz=0.f, sw=0.f;
    #pragma unroll 8
    for (int sl = 0; sl < 32; ++sl) {
        float4 v = *(const float4*)&ppart[(size_t)sl * SLICE_P + base];
        sx += v.x; sy += v.y; sz += v.z; sw += v.w;
    }
    *(float4*)&pool[base] = make_float4(sx, sy, sz, sw);
}

// vpart[cs][b][j] = sum_{c in 96-range} pool[b,h(j),c] * Wf[c,768+j]
__global__ void vals_k(const float* __restrict__ pool, const float* __restrict__ Wf,
                       float* __restrict__ vpart) {
    __shared__ float Ls[24][96];
    int b = blockIdx.x, cs = blockIdx.y, t = threadIdx.x;   // block = 768
    int c0 = cs * 96;
    for (int idx = t; idx < 24 * 96; idx += 768) {
        int hh = idx / 96, cc = idx % 96;
        Ls[hh][cc] = pool[((size_t)b * 24 + hh) * 768 + c0 + cc];
    }
    __syncthreads();
    int h = t >> 5;
    float acc = 0.f;
    for (int cc = 0; cc < 96; ++cc)
        acc += Ls[h][cc] * Wf[(size_t)(c0 + cc) * 1536 + 768 + t];
    vpart[((size_t)cs * 32 + b) * 768 + t] = acc;
}

// opart[cs][b][j] = sum_{c in 96-range} vals[b,c] * ow[c,j]
// vals[b,c] = kvb_V[c] + sum_cs' vpart (summed inline in LDS stage)
__global__ void oproj_k(const float* __restrict__ vpart, const float* __restrict__ kvb,
                        const float* __restrict__ ow, float* __restrict__ opart) {
    __shared__ float Vs[96];
    int b = blockIdx.x, cs = blockIdx.y, t = threadIdx.x;   // block = 768
    int c0 = cs * 96;
    if (t < 96) {
        float v = kvb[768 + c0 + t];
        #pragma unroll
        for (int s2 = 0; s2 < 8; ++s2) v += vpart[((size_t)s2 * 32 + b) * 768 + c0 + t];
        Vs[t] = v;
    }
    __syncthreads();
    float acc = 0.f;
    for (int cc = 0; cc < 96; ++cc)
        acc += Vs[cc] * ow[(size_t)(c0 + cc) * 768 + t];
    opart[((size_t)cs * 32 + b) * 768 + t] = acc;
}

// attn finish: y = latents+emb+ob+sum_cs opart; RMSNorm -> lat2
__global__ void attnfin_k(const float* __restrict__ opart, const float* __restrict__ ob,
                          const float* __restrict__ latents, const float* __restrict__ emb,
                          const float* __restrict__ nw, float* __restrict__ lat2) {
    int b = blockIdx.x, t = threadIdx.x;   // 768
    float y = latents[t] + emb[b * 768 + t] + ob[t];
    #pragma unroll
    for (int cs = 0; cs < 8; ++cs) y += opart[((size_t)cs * 32 + b) * 768 + t];
    float s = y * y;
    for (int off = 32; off > 0; off >>= 1) s += __shfl_down(s, off);
    __shared__ float red[12];
    if ((t & 63) == 0) red[t >> 6] = s;
    __syncthreads();
    float tot = 0.f;
    #pragma unroll
    for (int w = 0; w < 12; ++w) tot += red[w];
    float rstd = rsqrtf(tot / 768.0f + EPSV);
    lat2[b * 768 + t] = y * rstd * nw[t];
}

// GLU pre-activation partials: hbuf[b][j(P)], hbuf[b][3072+j(G)] += lat2-chunk @ gw
__global__ void glu_k(const float* __restrict__ lat2, const float* __restrict__ gw,
                      const float* __restrict__ gb, float* __restrict__ hbuf) {
    int jt = blockIdx.x, bg = blockIdx.y, cs = blockIdx.z, t = threadIdx.x;
    int j = jt * 256 + t;   // < 3072
    float accP[4] = {0.f,0.f,0.f,0.f}, accG[4] = {0.f,0.f,0.f,0.f};
    if (cs == 0) {
        float bp = gb[j], bgv = gb[j + 3072];
        #pragma unroll
        for (int bb = 0; bb < 4; ++bb) { accP[bb] = bp; accG[bb] = bgv; }
    }
    const float* __restrict__ l2 = &lat2[(size_t)(bg * 4) * 768 + cs * 256];
    for (int c = 0; c < 256; ++c) {
        float wp = gw[(size_t)(cs * 256 + c) * 6144 + j];
        float wg = gw[(size_t)(cs * 256 + c) * 6144 + 3072 + j];
        #pragma unroll
        for (int bb = 0; bb < 4; ++bb) {
            float lv = l2[bb * 768 + c];         // uniform -> s_load
            accP[bb] += lv * wp;
            accG[bb] += lv * wg;
        }
    }
    #pragma unroll
    for (int bb = 0; bb < 4; ++bb) {
        atomicAdd(&hbuf[(size_t)(bg * 4 + bb) * 6144 + j],        accP[bb]);
        atomicAdd(&hbuf[(size_t)(bg * 4 + bb) * 6144 + 3072 + j], accG[bb]);
    }
}

// silu finish: mlpin[b][j] = P * silu(G)
__global__ void gfin_k(const float* __restrict__ hbuf, float* __restrict__ mlpin) {
    int idx = blockIdx.x * 256 + threadIdx.x;   // < 98304
    int b = idx / 3072, j = idx % 3072;
    float P = hbuf[(size_t)b * 6144 + j];
    float G = hbuf[(size_t)b * 6144 + 3072 + j];
    mlpin[idx] = P * (G / (1.0f + __expf(-G)));
}

// mlp[b,j] += mlp_in[b, i-chunk] @ mlp_out_w[i-chunk, j]  (+bias once; pre-zeroed)
__global__ void mlpout_k(const float* __restrict__ mlpin, const float* __restrict__ mw,
                         const float* __restrict__ mb, float* __restrict__ mlp) {
    int jt = blockIdx.x, bg = blockIdx.y, ic = blockIdx.z, t = threadIdx.x;
    int j = jt * 256 + t;   // < 768
    int i0 = ic * 384;
    const float* __restrict__ mi = &mlpin[(size_t)(bg * 4) * 3072 + i0];
    float acc[4] = {0.f, 0.f, 0.f, 0.f};
    for (int i = 0; i < 384; ++i) {
        float w = mw[(size_t)(i0 + i) * 768 + j];
        #pragma unroll
        for (int bb = 0; bb < 4; ++bb)
            acc[bb] += mi[bb * 3072 + i] * w;    // uniform -> s_load
    }
    float bias = (ic == 0) ? mb[j] : 0.f;
    #pragma unroll
    for (int bb = 0; bb < 4; ++bb)
        atomicAdd(&mlp[(bg * 4 + bb) * 768 + j], acc[bb] + bias);
}

// final residual + RMSNorm -> out
__global__ void fnorm_k(const float* __restrict__ lat2, const float* __restrict__ mlp,
                        const float* __restrict__ nw, float* __restrict__ out) {
    int b = blockIdx.x, t = threadIdx.x;   // block = 768
    float y = lat2[b * 768 + t] + mlp[b * 768 + t];
    float s = y * y;
    for (int off = 32; off > 0; off >>= 1) s += __shfl_down(s, off);
    __shared__ float red[12];
    if ((t & 63) == 0) red[t >> 6] = s;
    __syncthreads();
    float tot = 0.f;
    #pragma unroll
    for (int w = 0; w < 12; ++w) tot += red[w];
    float rstd = rsqrtf(tot / 768.0f + EPSV);
    out[b * 768 + t] = y * rstd * nw[t];
}

extern "C" void kernel_launch(void* const* d_in, const int* in_sizes, int n_in,
                              void* d_out, int out_size, void* d_ws, size_t ws_size,
                              hipStream_t stream) {
    const float* x       = (const float*)d_in[0];
    const float* emb     = (const float*)d_in[1];
    const float* latents = (const float*)d_in[2];
    const float* proj_w  = (const float*)d_in[3];
    const float* proj_b  = (const float*)d_in[4];
    const float* q_w     = (const float*)d_in[5];
    const float* kv_w    = (const float*)d_in[6];
    const float* ao_w    = (const float*)d_in[7];
    const float* ao_b    = (const float*)d_in[8];
    const float* anw     = (const float*)d_in[9];
    const float* mnw     = (const float*)d_in[10];
    const float* glu_w   = (const float*)d_in[11];
    const float* glu_b   = (const float*)d_in[12];
    const float* mo_w    = (const float*)d_in[13];
    const float* mo_b    = (const float*)d_in[14];

    float* ws    = (float*)d_ws;
    float* Wf    = ws + OFF_WF;
    float* q     = ws + OFF_Q;
    float* wqT   = ws + OFF_WQ;
    float* Sp    = ws + OFF_S;
    float* ppart = ws + OFF_PPART;
    float* pool  = ws + OFF_POOL;
    float* mlp   = ws + OFF_MLP;
    float* kvb   = ws + OFF_KVB;
    float* hbuf  = ws + OFF_HBUF;
    float* vpart = ws + OFF_VPART;
    float* opart = ws + OFF_OPART;
    float* lat2  = ws + OFF_LAT2;
    float* mlpin = ws + OFF_MLPIN;

    // zero mlp + kvb + hbuf (contiguous) for atomic accumulation
    hipMemsetAsync(ws + ZERO_START, 0, (size_t)ZERO_FLOATS * sizeof(float), stream);

    wf_gemm<<<dim3(24, 24), 256, 0, stream>>>(proj_w, kv_w, Wf);
    kvbias_k<<<dim3(3, 4), 256, 0, stream>>>(proj_b, kv_w, kvb);
    q_k<<<dim3(3, 32), 256, 0, stream>>>(latents, emb, q_w, q);
    wq_k<<<dim3(24, 32), 256, 0, stream>>>(Wf, q, wqT);

    scores_k<<<dim3(16, 2, 32), 256, 0, stream>>>(x, wqT, Sp);
    softmax_k<<<dim3(768), 256, 0, stream>>>(Sp);
    pooled_k<<<dim3(32, 32), 192, 0, stream>>>(x, Sp, ppart);
    reduce_k<<<dim3(576), 256, 0, stream>>>(ppart, pool);

    vals_k<<<dim3(32, 8), 768, 0, stream>>>(pool, Wf, vpart);
    oproj_k<<<dim3(32, 8), 768, 0, stream>>>(vpart, kvb, ao_w, opart);
    attnfin_k<<<dim3(32), 768, 0, stream>>>(opart, ao_b, latents, emb, anw, lat2);

    glu_k<<<dim3(12, 8, 3), 256, 0, stream>>>(lat2, glu_w, glu_b, hbuf);
    gfin_k<<<dim3(384), 256, 0, stream>>>(hbuf, mlpin);
    mlpout_k<<<dim3(3, 8, 8), 256, 0, stream>>>(mlpin, mo_w, mo_b, mlp);
    fnorm_k<<<dim3(32), 768, 0, stream>>>(lat2, mlp, mnw, (float*)d_out);
}

// Round 13
// 440.388 us; speedup vs baseline: 2.8672x; 1.0422x over previous
//
#include <hip/hip_runtime.h>
#include <math.h>

#define BB 32
#define NN 4096
#define CC 768
#define HH 24
#define HID 3072
#define N2 1536   // 2*C
#define EPSV 1e-6f
#define SCALE 0.17677669529663687f  // 1/sqrt(32)

#define SLICE_S  ((size_t)BB*HH*NN)           // 3,145,728 (one cs score slice)
#define SLICE_P  ((size_t)BB*HH*CC)           // 589,824

// workspace offsets (in floats). MLP/KVB/HBUF contiguous -> single memset.
#define OFF_WF     0                          // 1,179,648
#define OFF_Q      (OFF_WF   + CC*N2)
#define OFF_WQ     (OFF_Q    + BB*CC)         // wqT: [b][c][24]
#define OFF_S      (OFF_WQ   + BB*HH*CC)      // Spart: [2][b][h][n]; slice0 = final S
#define OFF_PPART  (OFF_S    + 2*BB*HH*NN)    // [32][b][h][c]
#define OFF_POOL   (OFF_PPART+ 32*BB*HH*CC)
#define OFF_MLP    (OFF_POOL + BB*HH*CC)      // zeroed
#define OFF_KVB    (OFF_MLP  + BB*CC)         // zeroed
#define OFF_HBUF   (OFF_KVB  + N2)            // zeroed, [32][6144]
#define OFF_VPART  (OFF_HBUF + BB*2*HID)      // [8][b][768]
#define OFF_OPART  (OFF_VPART+ 8*BB*CC)       // [8][b][768]
#define OFF_LAT2   (OFF_OPART+ 8*BB*CC)
#define OFF_MLPIN  (OFF_LAT2 + BB*CC)
#define ZERO_START OFF_MLP
#define ZERO_FLOATS (BB*CC + N2 + BB*2*HID)

// ---------------------------------------------------------------------------
// Wf = proj_w (768x768) @ kv_w (768x1536).  BM=32 BN=64 BK=32, 2x4 micro-tile.
__global__ void wf_gemm(const float* __restrict__ A, const float* __restrict__ Bm,
                        float* __restrict__ Wf) {
    __shared__ float As[32][34];   // [kk][m], transposed
    __shared__ float Bs[32][68];   // [kk][n]
    int t = threadIdx.x;
    int tx = t & 15, ty = t >> 4;
    int n0 = blockIdx.x * 64, m0 = blockIdx.y * 32;
    int ar = t >> 3, ak4 = t & 7;
    int bk = t >> 4, bn4 = t & 15;
    const float* Ap  = &A[(size_t)(m0 + ar) * 768 + ak4 * 4];
    const float* Bp0 = &Bm[(size_t)bk * 1536 + n0 + bn4 * 4];
    const float* Bp1 = &Bm[(size_t)(bk + 16) * 1536 + n0 + bn4 * 4];
    float4 a_reg  = *(const float4*)Ap;
    float4 b_reg0 = *(const float4*)Bp0;
    float4 b_reg1 = *(const float4*)Bp1;
    float acc[2][4] = {};
    for (int kt = 0; kt < 24; ++kt) {
        __syncthreads();
        As[ak4 * 4 + 0][ar] = a_reg.x;
        As[ak4 * 4 + 1][ar] = a_reg.y;
        As[ak4 * 4 + 2][ar] = a_reg.z;
        As[ak4 * 4 + 3][ar] = a_reg.w;
        *(float4*)&Bs[bk][bn4 * 4]      = b_reg0;
        *(float4*)&Bs[bk + 16][bn4 * 4] = b_reg1;
        __syncthreads();
        if (kt < 23) {
            int k0 = (kt + 1) * 32;
            a_reg  = *(const float4*)(Ap + k0);
            b_reg0 = *(const float4*)(Bp0 + (size_t)k0 * 1536);
            b_reg1 = *(const float4*)(Bp1 + (size_t)k0 * 1536);
        }
        #pragma unroll
        for (int kk = 0; kk < 32; ++kk) {
            float a0 = As[kk][ty * 2], a1 = As[kk][ty * 2 + 1];
            float4 bv = *(const float4*)&Bs[kk][tx * 4];
            acc[0][0] += a0 * bv.x; acc[0][1] += a0 * bv.y;
            acc[0][2] += a0 * bv.z; acc[0][3] += a0 * bv.w;
            acc[1][0] += a1 * bv.x; acc[1][1] += a1 * bv.y;
            acc[1][2] += a1 * bv.z; acc[1][3] += a1 * bv.w;
        }
    }
    #pragma unroll
    for (int i = 0; i < 2; ++i) {
        int m = m0 + ty * 2 + i;
        *(float4*)&Wf[(size_t)m * 1536 + n0 + tx * 4] =
            make_float4(acc[i][0], acc[i][1], acc[i][2], acc[i][3]);
    }
}

// V-half bias only (K bias is constant over n -> cancels in softmax)
__global__ void kvbias_k(const float* __restrict__ pb, const float* __restrict__ kvw,
                         float* __restrict__ kvb) {
    int j = 768 + blockIdx.x * 256 + threadIdx.x;
    int i0 = blockIdx.y * 192;
    float acc = 0.f;
    for (int i = i0; i < i0 + 192; ++i) acc += pb[i] * kvw[(size_t)i * 1536 + j];
    atomicAdd(&kvb[j], acc);
}

// q[b,:] = (latents + emb[b]) @ q_w
__global__ void q_k(const float* __restrict__ latents, const float* __restrict__ emb,
                    const float* __restrict__ qw, float* __restrict__ q) {
    __shared__ float Ls[768];
    int b = blockIdx.y, t = threadIdx.x;
    for (int i = t; i < 768; i += 256) Ls[i] = latents[i] + emb[b * 768 + i];
    __syncthreads();
    int j = blockIdx.x * 256 + t;
    float acc = 0.f;
    for (int c = 0; c < 768; ++c) acc += Ls[c] * qw[c * 768 + j];
    q[b * 768 + j] = acc;
}

// wqT[b,c,h] = scale * sum_d Wf[c, h*32+d] * q[b,h*32+d]
__global__ void wq_k(const float* __restrict__ Wf, const float* __restrict__ q,
                     float* __restrict__ wqT) {
    int h = blockIdx.x, b = blockIdx.y, t = threadIdx.x;
    __shared__ float qh[32];
    if (t < 32) qh[t] = q[b * 768 + h * 32 + t];
    __syncthreads();
    for (int c = t; c < 768; c += 256) {
        const float4* wrow = (const float4*)&Wf[(size_t)c * 1536 + h * 32];
        float acc = 0.f;
        #pragma unroll
        for (int d4 = 0; d4 < 8; ++d4) {
            float4 w = wrow[d4];
            acc += w.x * qh[4*d4] + w.y * qh[4*d4+1] + w.z * qh[4*d4+2] + w.w * qh[4*d4+3];
        }
        wqT[((size_t)b * 768 + c) * 24 + h] = SCALE * acc;
    }
}

// Spart[cs][b][h][n] = x[b,n,cs-range] . wqT[b,cs-range,h]    (pass 1 over x)
// Wave-private LDS staging (NO barriers): each wave owns 64 rows + 8.25KB LDS.
__global__ void scores_k(const float* __restrict__ x, const float* __restrict__ wqT,
                         float* __restrict__ Spart) {
    __shared__ float Xs[4][64][33];
    int b = blockIdx.z, cs = blockIdx.y;
    int t = threadIdx.x;
    int w = t >> 6, lane = t & 63;
    int n0 = blockIdx.x * 256 + w * 64;
    int sr = lane >> 3, sc = (lane & 7) * 4;   // staging: 8 rows x 32 floats
    const float* __restrict__ xbase = &x[((size_t)b * 4096 + n0) * 768 + cs * 384];
    const float* __restrict__ wb = &wqT[((size_t)b * 768 + cs * 384) * 24];
    float (*Xw)[33] = Xs[w];
    float acc[24];
    #pragma unroll
    for (int h = 0; h < 24; ++h) acc[h] = 0.f;
    float4 pf[8];
    #pragma unroll
    for (int it = 0; it < 8; ++it)
        pf[it] = *(const float4*)&xbase[(size_t)(sr + 8 * it) * 768 + sc];
    for (int ck = 0; ck < 12; ++ck) {
        #pragma unroll
        for (int it = 0; it < 8; ++it) {
            int r = sr + 8 * it;
            Xw[r][sc + 0] = pf[it].x; Xw[r][sc + 1] = pf[it].y;
            Xw[r][sc + 2] = pf[it].z; Xw[r][sc + 3] = pf[it].w;
        }
        if (ck < 11) {
            #pragma unroll
            for (int it = 0; it < 8; ++it)
                pf[it] = *(const float4*)&xbase[(size_t)(sr + 8 * it) * 768 + (ck + 1) * 32 + sc];
        }
        const float* __restrict__ wc = &wb[ck * 32 * 24];
        #pragma unroll
        for (int cc = 0; cc < 32; ++cc) {
            float xv = Xw[lane][cc];
            #pragma unroll
            for (int h = 0; h < 24; ++h)
                acc[h] += xv * wc[cc * 24 + h];          // uniform -> s_load
        }
    }
    int n = n0 + lane;
    #pragma unroll
    for (int h = 0; h < 24; ++h)
        Spart[((size_t)(cs * 32 + b) * 24 + h) * 4096 + n] = acc[h];
}

// softmax over n: S = softmax(p0 + p1); writes into slice 0 (final S)
__global__ void softmax_k(float* __restrict__ Sp) {
    int row = blockIdx.x;            // b*24 + h
    int t = threadIdx.x;
    size_t base = (size_t)row * 4096;
    float v[16];
    float m = -1e30f;
    #pragma unroll
    for (int i = 0; i < 16; ++i) {
        int idx = t + 256 * i;
        v[i] = Sp[base + idx] + Sp[SLICE_S + base + idx];
        m = fmaxf(m, v[i]);
    }
    __shared__ float redm[4];
    for (int off = 32; off > 0; off >>= 1) m = fmaxf(m, __shfl_down(m, off));
    if ((t & 63) == 0) redm[t >> 6] = m;
    __syncthreads();
    m = fmaxf(fmaxf(redm[0], redm[1]), fmaxf(redm[2], redm[3]));
    float s = 0.f;
    #pragma unroll
    for (int i = 0; i < 16; ++i) { v[i] = __expf(v[i] - m); s += v[i]; }
    __shared__ float reds[4];
    for (int off = 32; off > 0; off >>= 1) s += __shfl_down(s, off);
    if ((t & 63) == 0) reds[t >> 6] = s;
    __syncthreads();
    s = reds[0] + reds[1] + reds[2] + reds[3];
    float inv = 1.0f / s;
    #pragma unroll
    for (int i = 0; i < 16; ++i) Sp[base + t + 256 * i] = v[i] * inv;
}

// ppart[nt][b][h][c] = sum_{n in chunk} S[b,h,n] * x[b,n,c]   (pass 2 over x)
// Weights via wave-uniform s_load; 96 VGPR accs; coalesced stores. PROVEN — do not touch.
__global__ void pooled_k(const float* __restrict__ x, const float* __restrict__ S,
                         float* __restrict__ ppart) {
    int nt = blockIdx.x, b = blockIdx.y;
    int t = threadIdx.x;          // 0..191
    int c = t * 4;
    int n0 = nt * 128;
    const float* __restrict__ Sb = &S[(size_t)b * 24 * 4096 + n0];
    const float* __restrict__ xb = &x[((size_t)b * 4096 + n0) * 768 + c];
    float ax[24], ay[24], az[24], aw[24];
    #pragma unroll
    for (int h = 0; h < 24; ++h) { ax[h]=0.f; ay[h]=0.f; az[h]=0.f; aw[h]=0.f; }
    #pragma unroll 4
    for (int i = 0; i < 128; ++i) {
        float4 xv = *(const float4*)&xb[(size_t)i * 768];
        #pragma unroll
        for (int h = 0; h < 24; ++h) {
            float s = Sb[h * 4096 + i];          // uniform -> s_load
            ax[h] += s * xv.x; ay[h] += s * xv.y;
            az[h] += s * xv.z; aw[h] += s * xv.w;
        }
    }
    float* dst = &ppart[(size_t)(nt * 32 + b) * 24 * 768];
    #pragma unroll
    for (int h = 0; h < 24; ++h)
        *(float4*)&dst[h * 768 + c] = make_float4(ax[h], ay[h], az[h], aw[h]);
}

// pool[i] = sum over 32 slices of ppart
__global__ void reduce_k(const float* __restrict__ ppart, float* __restrict__ pool) {
    size_t base = ((size_t)blockIdx.x * 256 + threadIdx.x) * 4;
    float sx=0.f, sy=0.f, sz=0.f, sw=0.f;
    #pragma unroll 8
    for (int sl = 0; sl < 32; ++sl) {
        float4 v = *(const float4*)&ppart[(size_t)sl * SLICE_P + base];
        sx += v.x; sy += v.y; sz += v.z; sw += v.w;
    }
    *(float4*)&pool[base] = make_float4(sx, sy, sz, sw);
}

// vpart[cs][b][j] = sum_{c in 96-range} pool[b,h(j),c] * Wf[c,768+j]
__global__ void vals_k(const float* __restrict__ pool, const float* __restrict__ Wf,
                       float* __restrict__ vpart) {
    __shared__ float Ls[24][96];
    int b = blockIdx.x, cs = blockIdx.y, t = threadIdx.x;   // block = 768
    int c0 = cs * 96;
    for (int idx = t; idx < 24 * 96; idx += 768) {
        int hh = idx / 96, cc = idx % 96;
        Ls[hh][cc] = pool[((size_t)b * 24 + hh) * 768 + c0 + cc];
    }
    __syncthreads();
    int h = t >> 5;
    float acc = 0.f;
    for (int cc = 0; cc < 96; ++cc)
        acc += Ls[h][cc] * Wf[(size_t)(c0 + cc) * 1536 + 768 + t];
    vpart[((size_t)cs * 32 + b) * 768 + t] = acc;
}

// opart[cs][b][j] = sum_{c in 96-range} vals[b,c] * ow[c,j]
// vals[b,c] = kvb_V[c] + sum_cs' vpart (summed inline in LDS stage)
__global__ void oproj_k(const float* __restrict__ vpart, const float* __restrict__ kvb,
                        const float* __restrict__ ow, float* __restrict__ opart) {
    __shared__ float Vs[96];
    int b = blockIdx.x, cs = blockIdx.y, t = threadIdx.x;   // block = 768
    int c0 = cs * 96;
    if (t < 96) {
        float v = kvb[768 + c0 + t];
        #pragma unroll
        for (int s2 = 0; s2 < 8; ++s2) v += vpart[((size_t)s2 * 32 + b) * 768 + c0 + t];
        Vs[t] = v;
    }
    __syncthreads();
    float acc = 0.f;
    for (int cc = 0; cc < 96; ++cc)
        acc += Vs[cc] * ow[(size_t)(c0 + cc) * 768 + t];
    opart[((size_t)cs * 32 + b) * 768 + t] = acc;
}

// attn finish: y = latents+emb+ob+sum_cs opart; RMSNorm -> lat2
__global__ void attnfin_k(const float* __restrict__ opart, const float* __restrict__ ob,
                          const float* __restrict__ latents, const float* __restrict__ emb,
                          const float* __restrict__ nw, float* __restrict__ lat2) {
    int b = blockIdx.x, t = threadIdx.x;   // 768
    float y = latents[t] + emb[b * 768 + t] + ob[t];
    #pragma unroll
    for (int cs = 0; cs < 8; ++cs) y += opart[((size_t)cs * 32 + b) * 768 + t];
    float s = y * y;
    for (int off = 32; off > 0; off >>= 1) s += __shfl_down(s, off);
    __shared__ float red[12];
    if ((t & 63) == 0) red[t >> 6] = s;
    __syncthreads();
    float tot = 0.f;
    #pragma unroll
    for (int w = 0; w < 12; ++w) tot += red[w];
    float rstd = rsqrtf(tot / 768.0f + EPSV);
    lat2[b * 768 + t] = y * rstd * nw[t];
}

// GLU pre-activation partials, 8 batches per block (gw redundancy 8x -> 4x):
// hbuf[b][j(P)], hbuf[b][3072+j(G)] += lat2[b, c-chunk] @ gw[c-chunk, :]
__global__ void glu_k(const float* __restrict__ lat2, const float* __restrict__ gw,
                      const float* __restrict__ gb, float* __restrict__ hbuf) {
    int jt = blockIdx.x, bg = blockIdx.y, cs = blockIdx.z, t = threadIdx.x;
    int j = jt * 256 + t;   // < 3072
    int b0 = bg * 8, c0 = cs * 128;
    float accP[8] = {}, accG[8] = {};
    if (cs == 0) {
        float bp = gb[j], bgv = gb[j + 3072];
        #pragma unroll
        for (int bb = 0; bb < 8; ++bb) { accP[bb] = bp; accG[bb] = bgv; }
    }
    const float* __restrict__ l2 = &lat2[(size_t)b0 * 768 + c0];
    for (int c = 0; c < 128; ++c) {
        float wp = gw[(size_t)(c0 + c) * 6144 + j];
        float wg = gw[(size_t)(c0 + c) * 6144 + 3072 + j];
        #pragma unroll
        for (int bb = 0; bb < 8; ++bb) {
            float lv = l2[bb * 768 + c];         // uniform -> s_load
            accP[bb] += lv * wp;
            accG[bb] += lv * wg;
        }
    }
    #pragma unroll
    for (int bb = 0; bb < 8; ++bb) {
        atomicAdd(&hbuf[(size_t)(b0 + bb) * 6144 + j],        accP[bb]);
        atomicAdd(&hbuf[(size_t)(b0 + bb) * 6144 + 3072 + j], accG[bb]);
    }
}

// silu finish: mlpin[b][j] = P * silu(G)
__global__ void gfin_k(const float* __restrict__ hbuf, float* __restrict__ mlpin) {
    int idx = blockIdx.x * 256 + threadIdx.x;   // < 98304
    int b = idx / 3072, j = idx % 3072;
    float P = hbuf[(size_t)b * 6144 + j];
    float G = hbuf[(size_t)b * 6144 + 3072 + j];
    mlpin[idx] = P * (G / (1.0f + __expf(-G)));
}

// mlp[b,j] += mlp_in[b, i-chunk] @ mlp_out_w[i-chunk, j]  (+bias once; pre-zeroed)
// i-chunk 192 -> 384 blocks (was 192: latency-starved)
__global__ void mlpout_k(const float* __restrict__ mlpin, const float* __restrict__ mw,
                         const float* __restrict__ mb, float* __restrict__ mlp) {
    int jt = blockIdx.x, bg = blockIdx.y, ic = blockIdx.z, t = threadIdx.x;
    int j = jt * 256 + t;   // < 768
    int i0 = ic * 192;
    const float* __restrict__ mi = &mlpin[(size_t)(bg * 4) * 3072 + i0];
    float acc[4] = {0.f, 0.f, 0.f, 0.f};
    for (int i = 0; i < 192; ++i) {
        float w = mw[(size_t)(i0 + i) * 768 + j];
        #pragma unroll
        for (int bb = 0; bb < 4; ++bb)
            acc[bb] += mi[bb * 3072 + i] * w;    // uniform -> s_load
    }
    float bias = (ic == 0) ? mb[j] : 0.f;
    #pragma unroll
    for (int bb = 0; bb < 4; ++bb)
        atomicAdd(&mlp[(bg * 4 + bb) * 768 + j], acc[bb] + bias);
}

// final residual + RMSNorm -> out
__global__ void fnorm_k(const float* __restrict__ lat2, const float* __restrict__ mlp,
                        const float* __restrict__ nw, float* __restrict__ out) {
    int b = blockIdx.x, t = threadIdx.x;   // block = 768
    float y = lat2[b * 768 + t] + mlp[b * 768 + t];
    float s = y * y;
    for (int off = 32; off > 0; off >>= 1) s += __shfl_down(s, off);
    __shared__ float red[12];
    if ((t & 63) == 0) red[t >> 6] = s;
    __syncthreads();
    float tot = 0.f;
    #pragma unroll
    for (int w = 0; w < 12; ++w) tot += red[w];
    float rstd = rsqrtf(tot / 768.0f + EPSV);
    out[b * 768 + t] = y * rstd * nw[t];
}

extern "C" void kernel_launch(void* const* d_in, const int* in_sizes, int n_in,
                              void* d_out, int out_size, void* d_ws, size_t ws_size,
                              hipStream_t stream) {
    const float* x       = (const float*)d_in[0];
    const float* emb     = (const float*)d_in[1];
    const float* latents = (const float*)d_in[2];
    const float* proj_w  = (const float*)d_in[3];
    const float* proj_b  = (const float*)d_in[4];
    const float* q_w     = (const float*)d_in[5];
    const float* kv_w    = (const float*)d_in[6];
    const float* ao_w    = (const float*)d_in[7];
    const float* ao_b    = (const float*)d_in[8];
    const float* anw     = (const float*)d_in[9];
    const float* mnw     = (const float*)d_in[10];
    const float* glu_w   = (const float*)d_in[11];
    const float* glu_b   = (const float*)d_in[12];
    const float* mo_w    = (const float*)d_in[13];
    const float* mo_b    = (const float*)d_in[14];

    float* ws    = (float*)d_ws;
    float* Wf    = ws + OFF_WF;
    float* q     = ws + OFF_Q;
    float* wqT   = ws + OFF_WQ;
    float* Sp    = ws + OFF_S;
    float* ppart = ws + OFF_PPART;
    float* pool  = ws + OFF_POOL;
    float* mlp   = ws + OFF_MLP;
    float* kvb   = ws + OFF_KVB;
    float* hbuf  = ws + OFF_HBUF;
    float* vpart = ws + OFF_VPART;
    float* opart = ws + OFF_OPART;
    float* lat2  = ws + OFF_LAT2;
    float* mlpin = ws + OFF_MLPIN;

    // zero mlp + kvb + hbuf (contiguous) for atomic accumulation
    hipMemsetAsync(ws + ZERO_START, 0, (size_t)ZERO_FLOATS * sizeof(float), stream);

    wf_gemm<<<dim3(24, 24), 256, 0, stream>>>(proj_w, kv_w, Wf);
    kvbias_k<<<dim3(3, 4), 256, 0, stream>>>(proj_b, kv_w, kvb);
    q_k<<<dim3(3, 32), 256, 0, stream>>>(latents, emb, q_w, q);
    wq_k<<<dim3(24, 32), 256, 0, stream>>>(Wf, q, wqT);

    scores_k<<<dim3(16, 2, 32), 256, 0, stream>>>(x, wqT, Sp);
    softmax_k<<<dim3(768), 256, 0, stream>>>(Sp);
    pooled_k<<<dim3(32, 32), 192, 0, stream>>>(x, Sp, ppart);
    reduce_k<<<dim3(576), 256, 0, stream>>>(ppart, pool);

    vals_k<<<dim3(32, 8), 768, 0, stream>>>(pool, Wf, vpart);
    oproj_k<<<dim3(32, 8), 768, 0, stream>>>(vpart, kvb, ao_w, opart);
    attnfin_k<<<dim3(32), 768, 0, stream>>>(opart, ao_b, latents, emb, anw, lat2);

    glu_k<<<dim3(12, 4, 6), 256, 0, stream>>>(lat2, glu_w, glu_b, hbuf);
    gfin_k<<<dim3(384), 256, 0, stream>>>(hbuf, mlpin);
    mlpout_k<<<dim3(3, 8, 16), 256, 0, stream>>>(mlpin, mo_w, mo_b, mlp);
    fnorm_k<<<dim3(32), 768, 0, stream>>>(lat2, mlp, mnw, (float*)d_out);
}

// Round 14
// 428.970 us; speedup vs baseline: 2.9435x; 1.0266x over previous
//
#include <hip/hip_runtime.h>
#include <math.h>

#define BB 32
#define NN 4096
#define CC 768
#define HH 24
#define HID 3072
#define N2 1536   // 2*C
#define EPSV 1e-6f
#define SCALE 0.17677669529663687f  // 1/sqrt(32)

#define SLICE_S  ((size_t)BB*HH*NN)           // 3,145,728 (one cs score slice)
#define SLICE_P  ((size_t)BB*HH*CC)           // 589,824

// workspace offsets (in floats). MLP/KVB/HBUF contiguous -> single memset.
#define OFF_WF     0                          // 1,179,648
#define OFF_Q      (OFF_WF   + CC*N2)
#define OFF_WQ     (OFF_Q    + BB*CC)         // wqT: [b][c][24]
#define OFF_S      (OFF_WQ   + BB*HH*CC)      // Spart: [2][b][h][n]; slice0 = final S
#define OFF_PPART  (OFF_S    + 2*BB*HH*NN)    // [16][b][h][c]
#define OFF_MLP    (OFF_PPART+ 16*BB*HH*CC)   // zeroed
#define OFF_KVB    (OFF_MLP  + BB*CC)         // zeroed
#define OFF_HBUF   (OFF_KVB  + N2)            // zeroed, [32][6144]
#define OFF_VPART  (OFF_HBUF + BB*2*HID)      // [8][b][768]
#define OFF_OPART  (OFF_VPART+ 8*BB*CC)       // [8][b][768]
#define OFF_LAT2   (OFF_OPART+ 8*BB*CC)
#define OFF_MLPIN  (OFF_LAT2 + BB*CC)
#define ZERO_START OFF_MLP
#define ZERO_FLOATS (BB*CC + N2 + BB*2*HID)

// ---------------------------------------------------------------------------
// Wf = proj_w (768x768) @ kv_w (768x1536).  BM=32 BN=64 BK=32, 2x4 micro-tile.
__global__ void wf_gemm(const float* __restrict__ A, const float* __restrict__ Bm,
                        float* __restrict__ Wf) {
    __shared__ float As[32][34];   // [kk][m], transposed
    __shared__ float Bs[32][68];   // [kk][n]
    int t = threadIdx.x;
    int tx = t & 15, ty = t >> 4;
    int n0 = blockIdx.x * 64, m0 = blockIdx.y * 32;
    int ar = t >> 3, ak4 = t & 7;
    int bk = t >> 4, bn4 = t & 15;
    const float* Ap  = &A[(size_t)(m0 + ar) * 768 + ak4 * 4];
    const float* Bp0 = &Bm[(size_t)bk * 1536 + n0 + bn4 * 4];
    const float* Bp1 = &Bm[(size_t)(bk + 16) * 1536 + n0 + bn4 * 4];
    float4 a_reg  = *(const float4*)Ap;
    float4 b_reg0 = *(const float4*)Bp0;
    float4 b_reg1 = *(const float4*)Bp1;
    float acc[2][4] = {};
    for (int kt = 0; kt < 24; ++kt) {
        __syncthreads();
        As[ak4 * 4 + 0][ar] = a_reg.x;
        As[ak4 * 4 + 1][ar] = a_reg.y;
        As[ak4 * 4 + 2][ar] = a_reg.z;
        As[ak4 * 4 + 3][ar] = a_reg.w;
        *(float4*)&Bs[bk][bn4 * 4]      = b_reg0;
        *(float4*)&Bs[bk + 16][bn4 * 4] = b_reg1;
        __syncthreads();
        if (kt < 23) {
            int k0 = (kt + 1) * 32;
            a_reg  = *(const float4*)(Ap + k0);
            b_reg0 = *(const float4*)(Bp0 + (size_t)k0 * 1536);
            b_reg1 = *(const float4*)(Bp1 + (size_t)k0 * 1536);
        }
        #pragma unroll
        for (int kk = 0; kk < 32; ++kk) {
            float a0 = As[kk][ty * 2], a1 = As[kk][ty * 2 + 1];
            float4 bv = *(const float4*)&Bs[kk][tx * 4];
            acc[0][0] += a0 * bv.x; acc[0][1] += a0 * bv.y;
            acc[0][2] += a0 * bv.z; acc[0][3] += a0 * bv.w;
            acc[1][0] += a1 * bv.x; acc[1][1] += a1 * bv.y;
            acc[1][2] += a1 * bv.z; acc[1][3] += a1 * bv.w;
        }
    }
    #pragma unroll
    for (int i = 0; i < 2; ++i) {
        int m = m0 + ty * 2 + i;
        *(float4*)&Wf[(size_t)m * 1536 + n0 + tx * 4] =
            make_float4(acc[i][0], acc[i][1], acc[i][2], acc[i][3]);
    }
}

// V-half bias only (K bias is constant over n -> cancels in softmax)
__global__ void kvbias_k(const float* __restrict__ pb, const float* __restrict__ kvw,
                         float* __restrict__ kvb) {
    int j = 768 + blockIdx.x * 256 + threadIdx.x;
    int i0 = blockIdx.y * 192;
    float acc = 0.f;
    for (int i = i0; i < i0 + 192; ++i) acc += pb[i] * kvw[(size_t)i * 1536 + j];
    atomicAdd(&kvb[j], acc);
}

// q[b,:] = (latents + emb[b]) @ q_w
__global__ void q_k(const float* __restrict__ latents, const float* __restrict__ emb,
                    const float* __restrict__ qw, float* __restrict__ q) {
    __shared__ float Ls[768];
    int b = blockIdx.y, t = threadIdx.x;
    for (int i = t; i < 768; i += 256) Ls[i] = latents[i] + emb[b * 768 + i];
    __syncthreads();
    int j = blockIdx.x * 256 + t;
    float acc = 0.f;
    for (int c = 0; c < 768; ++c) acc += Ls[c] * qw[c * 768 + j];
    q[b * 768 + j] = acc;
}

// wqT[b,c,h] = scale * sum_d Wf[c, h*32+d] * q[b,h*32+d]
__global__ void wq_k(const float* __restrict__ Wf, const float* __restrict__ q,
                     float* __restrict__ wqT) {
    int h = blockIdx.x, b = blockIdx.y, t = threadIdx.x;
    __shared__ float qh[32];
    if (t < 32) qh[t] = q[b * 768 + h * 32 + t];
    __syncthreads();
    for (int c = t; c < 768; c += 256) {
        const float4* wrow = (const float4*)&Wf[(size_t)c * 1536 + h * 32];
        float acc = 0.f;
        #pragma unroll
        for (int d4 = 0; d4 < 8; ++d4) {
            float4 w = wrow[d4];
            acc += w.x * qh[4*d4] + w.y * qh[4*d4+1] + w.z * qh[4*d4+2] + w.w * qh[4*d4+3];
        }
        wqT[((size_t)b * 768 + c) * 24 + h] = SCALE * acc;
    }
}

// Spart[cs][b][h][n] = x[b,n,cs-range] . wqT[b,cs-range,h]    (pass 1 over x)
// Wave-private LDS staging (NO barriers): each wave owns 64 rows + 8.25KB LDS.
__global__ void scores_k(const float* __restrict__ x, const float* __restrict__ wqT,
                         float* __restrict__ Spart) {
    __shared__ float Xs[4][64][33];
    int b = blockIdx.z, cs = blockIdx.y;
    int t = threadIdx.x;
    int w = t >> 6, lane = t & 63;
    int n0 = blockIdx.x * 256 + w * 64;
    int sr = lane >> 3, sc = (lane & 7) * 4;   // staging: 8 rows x 32 floats
    const float* __restrict__ xbase = &x[((size_t)b * 4096 + n0) * 768 + cs * 384];
    const float* __restrict__ wb = &wqT[((size_t)b * 768 + cs * 384) * 24];
    float (*Xw)[33] = Xs[w];
    float acc[24];
    #pragma unroll
    for (int h = 0; h < 24; ++h) acc[h] = 0.f;
    float4 pf[8];
    #pragma unroll
    for (int it = 0; it < 8; ++it)
        pf[it] = *(const float4*)&xbase[(size_t)(sr + 8 * it) * 768 + sc];
    for (int ck = 0; ck < 12; ++ck) {
        #pragma unroll
        for (int it = 0; it < 8; ++it) {
            int r = sr + 8 * it;
            Xw[r][sc + 0] = pf[it].x; Xw[r][sc + 1] = pf[it].y;
            Xw[r][sc + 2] = pf[it].z; Xw[r][sc + 3] = pf[it].w;
        }
        if (ck < 11) {
            #pragma unroll
            for (int it = 0; it < 8; ++it)
                pf[it] = *(const float4*)&xbase[(size_t)(sr + 8 * it) * 768 + (ck + 1) * 32 + sc];
        }
        const float* __restrict__ wc = &wb[ck * 32 * 24];
        #pragma unroll
        for (int cc = 0; cc < 32; ++cc) {
            float xv = Xw[lane][cc];
            #pragma unroll
            for (int h = 0; h < 24; ++h)
                acc[h] += xv * wc[cc * 24 + h];          // uniform -> s_load
        }
    }
    int n = n0 + lane;
    #pragma unroll
    for (int h = 0; h < 24; ++h)
        Spart[((size_t)(cs * 32 + b) * 24 + h) * 4096 + n] = acc[h];
}

// softmax over n: S = softmax(p0 + p1); writes into slice 0 (final S)
__global__ void softmax_k(float* __restrict__ Sp) {
    int row = blockIdx.x;            // b*24 + h
    int t = threadIdx.x;
    size_t base = (size_t)row * 4096;
    float v[16];
    float m = -1e30f;
    #pragma unroll
    for (int i = 0; i < 16; ++i) {
        int idx = t + 256 * i;
        v[i] = Sp[base + idx] + Sp[SLICE_S + base + idx];
        m = fmaxf(m, v[i]);
    }
    __shared__ float redm[4];
    for (int off = 32; off > 0; off >>= 1) m = fmaxf(m, __shfl_down(m, off));
    if ((t & 63) == 0) redm[t >> 6] = m;
    __syncthreads();
    m = fmaxf(fmaxf(redm[0], redm[1]), fmaxf(redm[2], redm[3]));
    float s = 0.f;
    #pragma unroll
    for (int i = 0; i < 16; ++i) { v[i] = __expf(v[i] - m); s += v[i]; }
    __shared__ float reds[4];
    for (int off = 32; off > 0; off >>= 1) s += __shfl_down(s, off);
    if ((t & 63) == 0) reds[t >> 6] = s;
    __syncthreads();
    s = reds[0] + reds[1] + reds[2] + reds[3];
    float inv = 1.0f / s;
    #pragma unroll
    for (int i = 0; i < 16; ++i) Sp[base + t + 256 * i] = v[i] * inv;
}

// ppart[nt][b][h][c] = sum_{n in 256-chunk} S[b,h,n] * x[b,n,c]  (pass 2 over x)
// Body identical to proven version; only the chunk length changed (128 -> 256).
__global__ void pooled_k(const float* __restrict__ x, const float* __restrict__ S,
                         float* __restrict__ ppart) {
    int nt = blockIdx.x, b = blockIdx.y;
    int t = threadIdx.x;          // 0..191
    int c = t * 4;
    int n0 = nt * 256;
    const float* __restrict__ Sb = &S[(size_t)b * 24 * 4096 + n0];
    const float* __restrict__ xb = &x[((size_t)b * 4096 + n0) * 768 + c];
    float ax[24], ay[24], az[24], aw[24];
    #pragma unroll
    for (int h = 0; h < 24; ++h) { ax[h]=0.f; ay[h]=0.f; az[h]=0.f; aw[h]=0.f; }
    #pragma unroll 4
    for (int i = 0; i < 256; ++i) {
        float4 xv = *(const float4*)&xb[(size_t)i * 768];
        #pragma unroll
        for (int h = 0; h < 24; ++h) {
            float s = Sb[h * 4096 + i];          // uniform -> s_load
            ax[h] += s * xv.x; ay[h] += s * xv.y;
            az[h] += s * xv.z; aw[h] += s * xv.w;
        }
    }
    float* dst = &ppart[(size_t)(nt * 32 + b) * 24 * 768];
    #pragma unroll
    for (int h = 0; h < 24; ++h)
        *(float4*)&dst[h * 768 + c] = make_float4(ax[h], ay[h], az[h], aw[h]);
}

// vpart[cs][b][j] = sum_{c in 96-range} (sum_nt ppart[nt][b][h(j)][c]) * Wf[c,768+j]
// reduce_k folded into the LDS stage: slices summed inline.
__global__ void vals_k(const float* __restrict__ ppart, const float* __restrict__ Wf,
                       float* __restrict__ vpart) {
    __shared__ float Ls[24][96];
    int b = blockIdx.x, cs = blockIdx.y, t = threadIdx.x;   // block = 768
    int c0 = cs * 96;
    for (int idx = t; idx < 24 * 96; idx += 768) {
        int hh = idx / 96, cc = idx % 96;
        size_t base = (size_t)b * 24 * 768 + hh * 768 + c0 + cc;
        float s = 0.f;
        #pragma unroll 4
        for (int sl = 0; sl < 16; ++sl)
            s += ppart[(size_t)sl * 32 * 24 * 768 + base];
        Ls[hh][cc] = s;
    }
    __syncthreads();
    int h = t >> 5;
    float acc = 0.f;
    for (int cc = 0; cc < 96; ++cc)
        acc += Ls[h][cc] * Wf[(size_t)(c0 + cc) * 1536 + 768 + t];
    vpart[((size_t)cs * 32 + b) * 768 + t] = acc;
}

// opart[cs][b][j] = sum_{c in 96-range} vals[b,c] * ow[c,j]
// vals[b,c] = kvb_V[c] + sum_cs' vpart (summed inline in LDS stage)
__global__ void oproj_k(const float* __restrict__ vpart, const float* __restrict__ kvb,
                        const float* __restrict__ ow, float* __restrict__ opart) {
    __shared__ float Vs[96];
    int b = blockIdx.x, cs = blockIdx.y, t = threadIdx.x;   // block = 768
    int c0 = cs * 96;
    if (t < 96) {
        float v = kvb[768 + c0 + t];
        #pragma unroll
        for (int s2 = 0; s2 < 8; ++s2) v += vpart[((size_t)s2 * 32 + b) * 768 + c0 + t];
        Vs[t] = v;
    }
    __syncthreads();
    float acc = 0.f;
    for (int cc = 0; cc < 96; ++cc)
        acc += Vs[cc] * ow[(size_t)(c0 + cc) * 768 + t];
    opart[((size_t)cs * 32 + b) * 768 + t] = acc;
}

// attn finish: y = latents+emb+ob+sum_cs opart; RMSNorm -> lat2
__global__ void attnfin_k(const float* __restrict__ opart, const float* __restrict__ ob,
                          const float* __restrict__ latents, const float* __restrict__ emb,
                          const float* __restrict__ nw, float* __restrict__ lat2) {
    int b = blockIdx.x, t = threadIdx.x;   // 768
    float y = latents[t] + emb[b * 768 + t] + ob[t];
    #pragma unroll
    for (int cs = 0; cs < 8; ++cs) y += opart[((size_t)cs * 32 + b) * 768 + t];
    float s = y * y;
    for (int off = 32; off > 0; off >>= 1) s += __shfl_down(s, off);
    __shared__ float red[12];
    if ((t & 63) == 0) red[t >> 6] = s;
    __syncthreads();
    float tot = 0.f;
    #pragma unroll
    for (int w = 0; w < 12; ++w) tot += red[w];
    float rstd = rsqrtf(tot / 768.0f + EPSV);
    lat2[b * 768 + t] = y * rstd * nw[t];
}

// GLU pre-activation partials, 8 batches per block (gw redundancy 4x):
// hbuf[b][j(P)], hbuf[b][3072+j(G)] += lat2[b, c-chunk] @ gw[c-chunk, :]
__global__ void glu_k(const float* __restrict__ lat2, const float* __restrict__ gw,
                      const float* __restrict__ gb, float* __restrict__ hbuf) {
    int jt = blockIdx.x, bg = blockIdx.y, cs = blockIdx.z, t = threadIdx.x;
    int j = jt * 256 + t;   // < 3072
    int b0 = bg * 8, c0 = cs * 128;
    float accP[8] = {}, accG[8] = {};
    if (cs == 0) {
        float bp = gb[j], bgv = gb[j + 3072];
        #pragma unroll
        for (int bb = 0; bb < 8; ++bb) { accP[bb] = bp; accG[bb] = bgv; }
    }
    const float* __restrict__ l2 = &lat2[(size_t)b0 * 768 + c0];
    for (int c = 0; c < 128; ++c) {
        float wp = gw[(size_t)(c0 + c) * 6144 + j];
        float wg = gw[(size_t)(c0 + c) * 6144 + 3072 + j];
        #pragma unroll
        for (int bb = 0; bb < 8; ++bb) {
            float lv = l2[bb * 768 + c];         // uniform -> s_load
            accP[bb] += lv * wp;
            accG[bb] += lv * wg;
        }
    }
    #pragma unroll
    for (int bb = 0; bb < 8; ++bb) {
        atomicAdd(&hbuf[(size_t)(b0 + bb) * 6144 + j],        accP[bb]);
        atomicAdd(&hbuf[(size_t)(b0 + bb) * 6144 + 3072 + j], accG[bb]);
    }
}

// silu finish: mlpin[b][j] = P * silu(G)
__global__ void gfin_k(const float* __restrict__ hbuf, float* __restrict__ mlpin) {
    int idx = blockIdx.x * 256 + threadIdx.x;   // < 98304
    int b = idx / 3072, j = idx % 3072;
    float P = hbuf[(size_t)b * 6144 + j];
    float G = hbuf[(size_t)b * 6144 + 3072 + j];
    mlpin[idx] = P * (G / (1.0f + __expf(-G)));
}

// mlp[b,j] += mlp_in[b, i-chunk] @ mlp_out_w[i-chunk, j]  (+bias once; pre-zeroed)
__global__ void mlpout_k(const float* __restrict__ mlpin, const float* __restrict__ mw,
                         const float* __restrict__ mb, float* __restrict__ mlp) {
    int jt = blockIdx.x, bg = blockIdx.y, ic = blockIdx.z, t = threadIdx.x;
    int j = jt * 256 + t;   // < 768
    int i0 = ic * 192;
    const float* __restrict__ mi = &mlpin[(size_t)(bg * 4) * 3072 + i0];
    float acc[4] = {0.f, 0.f, 0.f, 0.f};
    for (int i = 0; i < 192; ++i) {
        float w = mw[(size_t)(i0 + i) * 768 + j];
        #pragma unroll
        for (int bb = 0; bb < 4; ++bb)
            acc[bb] += mi[bb * 3072 + i] * w;    // uniform -> s_load
    }
    float bias = (ic == 0) ? mb[j] : 0.f;
    #pragma unroll
    for (int bb = 0; bb < 4; ++bb)
        atomicAdd(&mlp[(bg * 4 + bb) * 768 + j], acc[bb] + bias);
}

// final residual + RMSNorm -> out
__global__ void fnorm_k(const float* __restrict__ lat2, const float* __restrict__ mlp,
                        const float* __restrict__ nw, float* __restrict__ out) {
    int b = blockIdx.x, t = threadIdx.x;   // block = 768
    float y = lat2[b * 768 + t] + mlp[b * 768 + t];
    float s = y * y;
    for (int off = 32; off > 0; off >>= 1) s += __shfl_down(s, off);
    __shared__ float red[12];
    if ((t & 63) == 0) red[t >> 6] = s;
    __syncthreads();
    float tot = 0.f;
    #pragma unroll
    for (int w = 0; w < 12; ++w) tot += red[w];
    float rstd = rsqrtf(tot / 768.0f + EPSV);
    out[b * 768 + t] = y * rstd * nw[t];
}

extern "C" void kernel_launch(void* const* d_in, const int* in_sizes, int n_in,
                              void* d_out, int out_size, void* d_ws, size_t ws_size,
                              hipStream_t stream) {
    const float* x       = (const float*)d_in[0];
    const float* emb     = (const float*)d_in[1];
    const float* latents = (const float*)d_in[2];
    const float* proj_w  = (const float*)d_in[3];
    const float* proj_b  = (const float*)d_in[4];
    const float* q_w     = (const float*)d_in[5];
    const float* kv_w    = (const float*)d_in[6];
    const float* ao_w    = (const float*)d_in[7];
    const float* ao_b    = (const float*)d_in[8];
    const float* anw     = (const float*)d_in[9];
    const float* mnw     = (const float*)d_in[10];
    const float* glu_w   = (const float*)d_in[11];
    const float* glu_b   = (const float*)d_in[12];
    const float* mo_w    = (const float*)d_in[13];
    const float* mo_b    = (const float*)d_in[14];

    float* ws    = (float*)d_ws;
    float* Wf    = ws + OFF_WF;
    float* q     = ws + OFF_Q;
    float* wqT   = ws + OFF_WQ;
    float* Sp    = ws + OFF_S;
    float* ppart = ws + OFF_PPART;
    float* mlp   = ws + OFF_MLP;
    float* kvb   = ws + OFF_KVB;
    float* hbuf  = ws + OFF_HBUF;
    float* vpart = ws + OFF_VPART;
    float* opart = ws + OFF_OPART;
    float* lat2  = ws + OFF_LAT2;
    float* mlpin = ws + OFF_MLPIN;

    // zero mlp + kvb + hbuf (contiguous) for atomic accumulation
    hipMemsetAsync(ws + ZERO_START, 0, (size_t)ZERO_FLOATS * sizeof(float), stream);

    wf_gemm<<<dim3(24, 24), 256, 0, stream>>>(proj_w, kv_w, Wf);
    kvbias_k<<<dim3(3, 4), 256, 0, stream>>>(proj_b, kv_w, kvb);
    q_k<<<dim3(3, 32), 256, 0, stream>>>(latents, emb, q_w, q);
    wq_k<<<dim3(24, 32), 256, 0, stream>>>(Wf, q, wqT);

    scores_k<<<dim3(16, 2, 32), 256, 0, stream>>>(x, wqT, Sp);
    softmax_k<<<dim3(768), 256, 0, stream>>>(Sp);
    pooled_k<<<dim3(16, 32), 192, 0, stream>>>(x, Sp, ppart);

    vals_k<<<dim3(32, 8), 768, 0, stream>>>(ppart, Wf, vpart);
    oproj_k<<<dim3(32, 8), 768, 0, stream>>>(vpart, kvb, ao_w, opart);
    attnfin_k<<<dim3(32), 768, 0, stream>>>(opart, ao_b, latents, emb, anw, lat2);

    glu_k<<<dim3(12, 4, 6), 256, 0, stream>>>(lat2, glu_w, glu_b, hbuf);
    gfin_k<<<dim3(384), 256, 0, stream>>>(hbuf, mlpin);
    mlpout_k<<<dim3(3, 8, 16), 256, 0, stream>>>(mlpin, mo_w, mo_b, mlp);
    fnorm_k<<<dim3(32), 768, 0, stream>>>(lat2, mlp, mnw, (float*)d_out);
}

// Round 15
// 397.659 us; speedup vs baseline: 3.1752x; 1.0787x over previous
//
#include <hip/hip_runtime.h>
#include <math.h>

#define BB 32
#define NN 4096
#define CC 768
#define HH 24
#define HID 3072
#define N2 1536   // 2*C
#define EPSV 1e-6f
#define SCALE 0.17677669529663687f  // 1/sqrt(32)

#define SLICE_S  ((size_t)BB*HH*NN)           // 3,145,728 (one cs score slice)

// workspace offsets (in floats). MLP/KVB/HBUF/Q contiguous -> single memset.
#define OFF_WF     0                          // 1,179,648
#define OFF_WQ     (OFF_WF   + CC*N2)         // wqT: [b][c][24]
#define OFF_S      (OFF_WQ   + BB*HH*CC)      // Spart: [2][b][h][n]; slice0 = final S
#define OFF_PPART  (OFF_S    + 2*BB*HH*NN)    // [16][b][h][c]
#define OFF_MLP    (OFF_PPART+ 16*BB*HH*CC)   // zeroed
#define OFF_KVB    (OFF_MLP  + BB*CC)         // zeroed
#define OFF_HBUF   (OFF_KVB  + N2)            // zeroed, [32][6144]
#define OFF_Q      (OFF_HBUF + BB*2*HID)      // zeroed (atomic accum)
#define OFF_VPART  (OFF_Q    + BB*CC)         // [8][b][768]
#define OFF_OPART  (OFF_VPART+ 8*BB*CC)       // [8][b][768]
#define OFF_LAT2   (OFF_OPART+ 8*BB*CC)
#define OFF_MLPIN  (OFF_LAT2 + BB*CC)
#define ZERO_START OFF_MLP
#define ZERO_FLOATS (BB*CC + N2 + BB*2*HID + BB*CC)

// ---------------------------------------------------------------------------
// Wf = proj_w (768x768) @ kv_w (768x1536).  BM=32 BN=64 BK=32, 2x4 micro-tile.
__global__ void wf_gemm(const float* __restrict__ A, const float* __restrict__ Bm,
                        float* __restrict__ Wf) {
    __shared__ float As[32][34];   // [kk][m], transposed
    __shared__ float Bs[32][68];   // [kk][n]
    int t = threadIdx.x;
    int tx = t & 15, ty = t >> 4;
    int n0 = blockIdx.x * 64, m0 = blockIdx.y * 32;
    int ar = t >> 3, ak4 = t & 7;
    int bk = t >> 4, bn4 = t & 15;
    const float* Ap  = &A[(size_t)(m0 + ar) * 768 + ak4 * 4];
    const float* Bp0 = &Bm[(size_t)bk * 1536 + n0 + bn4 * 4];
    const float* Bp1 = &Bm[(size_t)(bk + 16) * 1536 + n0 + bn4 * 4];
    float4 a_reg  = *(const float4*)Ap;
    float4 b_reg0 = *(const float4*)Bp0;
    float4 b_reg1 = *(const float4*)Bp1;
    float acc[2][4] = {};
    for (int kt = 0; kt < 24; ++kt) {
        __syncthreads();
        As[ak4 * 4 + 0][ar] = a_reg.x;
        As[ak4 * 4 + 1][ar] = a_reg.y;
        As[ak4 * 4 + 2][ar] = a_reg.z;
        As[ak4 * 4 + 3][ar] = a_reg.w;
        *(float4*)&Bs[bk][bn4 * 4]      = b_reg0;
        *(float4*)&Bs[bk + 16][bn4 * 4] = b_reg1;
        __syncthreads();
        if (kt < 23) {
            int k0 = (kt + 1) * 32;
            a_reg  = *(const float4*)(Ap + k0);
            b_reg0 = *(const float4*)(Bp0 + (size_t)k0 * 1536);
            b_reg1 = *(const float4*)(Bp1 + (size_t)k0 * 1536);
        }
        #pragma unroll
        for (int kk = 0; kk < 32; ++kk) {
            float a0 = As[kk][ty * 2], a1 = As[kk][ty * 2 + 1];
            float4 bv = *(const float4*)&Bs[kk][tx * 4];
            acc[0][0] += a0 * bv.x; acc[0][1] += a0 * bv.y;
            acc[0][2] += a0 * bv.z; acc[0][3] += a0 * bv.w;
            acc[1][0] += a1 * bv.x; acc[1][1] += a1 * bv.y;
            acc[1][2] += a1 * bv.z; acc[1][3] += a1 * bv.w;
        }
    }
    #pragma unroll
    for (int i = 0; i < 2; ++i) {
        int m = m0 + ty * 2 + i;
        *(float4*)&Wf[(size_t)m * 1536 + n0 + tx * 4] =
            make_float4(acc[i][0], acc[i][1], acc[i][2], acc[i][3]);
    }
}

// V-half bias only (K bias cancels in softmax). i-split x16 (48 blocks).
__global__ void kvbias_k(const float* __restrict__ pb, const float* __restrict__ kvw,
                         float* __restrict__ kvb) {
    int j = 768 + blockIdx.x * 256 + threadIdx.x;
    int i0 = blockIdx.y * 48;
    float acc = 0.f;
    for (int i = i0; i < i0 + 48; ++i) acc += pb[i] * kvw[(size_t)i * 1536 + j];
    atomicAdd(&kvb[j], acc);
}

// q[b,j] += (latents + emb[b])[c-chunk] @ q_w[c-chunk, j]   (q pre-zeroed; c-split x4)
__global__ void q_k(const float* __restrict__ latents, const float* __restrict__ emb,
                    const float* __restrict__ qw, float* __restrict__ q) {
    __shared__ float Ls[192];
    int b = blockIdx.y, cs = blockIdx.z, t = threadIdx.x;
    int c0 = cs * 192;
    if (t < 192) Ls[t] = latents[c0 + t] + emb[b * 768 + c0 + t];
    __syncthreads();
    int j = blockIdx.x * 256 + t;
    float acc = 0.f;
    for (int c = 0; c < 192; ++c) acc += Ls[c] * qw[(size_t)(c0 + c) * 768 + j];
    atomicAdd(&q[b * 768 + j], acc);
}

// wqT[b,c,h] = scale * sum_d Wf[c, h*32+d] * q[b,h*32+d]   (2 batches/block)
__global__ void wq_k(const float* __restrict__ Wf, const float* __restrict__ q,
                     float* __restrict__ wqT) {
    int h = blockIdx.x, b0 = blockIdx.y * 2, t = threadIdx.x;
    __shared__ float qh[2][32];
    if (t < 64) qh[t >> 5][t & 31] = q[(b0 + (t >> 5)) * 768 + h * 32 + (t & 31)];
    __syncthreads();
    for (int c = t; c < 768; c += 256) {
        const float4* wrow = (const float4*)&Wf[(size_t)c * 1536 + h * 32];
        float a0 = 0.f, a1 = 0.f;
        #pragma unroll
        for (int d4 = 0; d4 < 8; ++d4) {
            float4 w = wrow[d4];
            a0 += w.x * qh[0][4*d4] + w.y * qh[0][4*d4+1] + w.z * qh[0][4*d4+2] + w.w * qh[0][4*d4+3];
            a1 += w.x * qh[1][4*d4] + w.y * qh[1][4*d4+1] + w.z * qh[1][4*d4+2] + w.w * qh[1][4*d4+3];
        }
        wqT[((size_t)(b0 + 0) * 768 + c) * 24 + h] = SCALE * a0;
        wqT[((size_t)(b0 + 1) * 768 + c) * 24 + h] = SCALE * a1;
    }
}

// Spart[cs][b][h][n] = x[b,n,cs-range] . wqT[b,cs-range,h]    (pass 1 over x)
// Wave-private LDS staging (NO barriers). PROVEN — do not touch.
__global__ void scores_k(const float* __restrict__ x, const float* __restrict__ wqT,
                         float* __restrict__ Spart) {
    __shared__ float Xs[4][64][33];
    int b = blockIdx.z, cs = blockIdx.y;
    int t = threadIdx.x;
    int w = t >> 6, lane = t & 63;
    int n0 = blockIdx.x * 256 + w * 64;
    int sr = lane >> 3, sc = (lane & 7) * 4;   // staging: 8 rows x 32 floats
    const float* __restrict__ xbase = &x[((size_t)b * 4096 + n0) * 768 + cs * 384];
    const float* __restrict__ wb = &wqT[((size_t)b * 768 + cs * 384) * 24];
    float (*Xw)[33] = Xs[w];
    float acc[24];
    #pragma unroll
    for (int h = 0; h < 24; ++h) acc[h] = 0.f;
    float4 pf[8];
    #pragma unroll
    for (int it = 0; it < 8; ++it)
        pf[it] = *(const float4*)&xbase[(size_t)(sr + 8 * it) * 768 + sc];
    for (int ck = 0; ck < 12; ++ck) {
        #pragma unroll
        for (int it = 0; it < 8; ++it) {
            int r = sr + 8 * it;
            Xw[r][sc + 0] = pf[it].x; Xw[r][sc + 1] = pf[it].y;
            Xw[r][sc + 2] = pf[it].z; Xw[r][sc + 3] = pf[it].w;
        }
        if (ck < 11) {
            #pragma unroll
            for (int it = 0; it < 8; ++it)
                pf[it] = *(const float4*)&xbase[(size_t)(sr + 8 * it) * 768 + (ck + 1) * 32 + sc];
        }
        const float* __restrict__ wc = &wb[ck * 32 * 24];
        #pragma unroll
        for (int cc = 0; cc < 32; ++cc) {
            float xv = Xw[lane][cc];
            #pragma unroll
            for (int h = 0; h < 24; ++h)
                acc[h] += xv * wc[cc * 24 + h];          // uniform -> s_load
        }
    }
    int n = n0 + lane;
    #pragma unroll
    for (int h = 0; h < 24; ++h)
        Spart[((size_t)(cs * 32 + b) * 24 + h) * 4096 + n] = acc[h];
}

// softmax over n: S = softmax(p0 + p1); writes into slice 0 (final S)
__global__ void softmax_k(float* __restrict__ Sp) {
    int row = blockIdx.x;            // b*24 + h
    int t = threadIdx.x;
    size_t base = (size_t)row * 4096;
    float v[16];
    float m = -1e30f;
    #pragma unroll
    for (int i = 0; i < 16; ++i) {
        int idx = t + 256 * i;
        v[i] = Sp[base + idx] + Sp[SLICE_S + base + idx];
        m = fmaxf(m, v[i]);
    }
    __shared__ float redm[4];
    for (int off = 32; off > 0; off >>= 1) m = fmaxf(m, __shfl_down(m, off));
    if ((t & 63) == 0) redm[t >> 6] = m;
    __syncthreads();
    m = fmaxf(fmaxf(redm[0], redm[1]), fmaxf(redm[2], redm[3]));
    float s = 0.f;
    #pragma unroll
    for (int i = 0; i < 16; ++i) { v[i] = __expf(v[i] - m); s += v[i]; }
    __shared__ float reds[4];
    for (int off = 32; off > 0; off >>= 1) s += __shfl_down(s, off);
    if ((t & 63) == 0) reds[t >> 6] = s;
    __syncthreads();
    s = reds[0] + reds[1] + reds[2] + reds[3];
    float inv = 1.0f / s;
    #pragma unroll
    for (int i = 0; i < 16; ++i) Sp[base + t + 256 * i] = v[i] * inv;
}

// ppart[nt][b][h][c] = sum_{n in 256-chunk} S[b,h,n] * x[b,n,c]  (pass 2 over x)
// PROVEN — do not touch.
__global__ void pooled_k(const float* __restrict__ x, const float* __restrict__ S,
                         float* __restrict__ ppart) {
    int nt = blockIdx.x, b = blockIdx.y;
    int t = threadIdx.x;          // 0..191
    int c = t * 4;
    int n0 = nt * 256;
    const float* __restrict__ Sb = &S[(size_t)b * 24 * 4096 + n0];
    const float* __restrict__ xb = &x[((size_t)b * 4096 + n0) * 768 + c];
    float ax[24], ay[24], az[24], aw[24];
    #pragma unroll
    for (int h = 0; h < 24; ++h) { ax[h]=0.f; ay[h]=0.f; az[h]=0.f; aw[h]=0.f; }
    #pragma unroll 4
    for (int i = 0; i < 256; ++i) {
        float4 xv = *(const float4*)&xb[(size_t)i * 768];
        #pragma unroll
        for (int h = 0; h < 24; ++h) {
            float s = Sb[h * 4096 + i];          // uniform -> s_load
            ax[h] += s * xv.x; ay[h] += s * xv.y;
            az[h] += s * xv.z; aw[h] += s * xv.w;
        }
    }
    float* dst = &ppart[(size_t)(nt * 32 + b) * 24 * 768];
    #pragma unroll
    for (int h = 0; h < 24; ++h)
        *(float4*)&dst[h * 768 + c] = make_float4(ax[h], ay[h], az[h], aw[h]);
}

// vpart[cs][b][j] = sum_{c in 96-range} (sum_nt ppart[nt][b][h(j)][c]) * Wf[c,768+j]
__global__ void vals_k(const float* __restrict__ ppart, const float* __restrict__ Wf,
                       float* __restrict__ vpart) {
    __shared__ float Ls[24][96];
    int b = blockIdx.x, cs = blockIdx.y, t = threadIdx.x;   // block = 768
    int c0 = cs * 96;
    for (int idx = t; idx < 24 * 96; idx += 768) {
        int hh = idx / 96, cc = idx % 96;
        size_t base = (size_t)b * 24 * 768 + hh * 768 + c0 + cc;
        float s = 0.f;
        #pragma unroll 4
        for (int sl = 0; sl < 16; ++sl)
            s += ppart[(size_t)sl * 32 * 24 * 768 + base];
        Ls[hh][cc] = s;
    }
    __syncthreads();
    int h = t >> 5;
    float acc = 0.f;
    for (int cc = 0; cc < 96; ++cc)
        acc += Ls[h][cc] * Wf[(size_t)(c0 + cc) * 1536 + 768 + t];
    vpart[((size_t)cs * 32 + b) * 768 + t] = acc;
}

// opart[cs][b][j] = sum_{c in 96-range} vals[b,c] * ow[c,j]
__global__ void oproj_k(const float* __restrict__ vpart, const float* __restrict__ kvb,
                        const float* __restrict__ ow, float* __restrict__ opart) {
    __shared__ float Vs[96];
    int b = blockIdx.x, cs = blockIdx.y, t = threadIdx.x;   // block = 768
    int c0 = cs * 96;
    if (t < 96) {
        float v = kvb[768 + c0 + t];
        #pragma unroll
        for (int s2 = 0; s2 < 8; ++s2) v += vpart[((size_t)s2 * 32 + b) * 768 + c0 + t];
        Vs[t] = v;
    }
    __syncthreads();
    float acc = 0.f;
    for (int cc = 0; cc < 96; ++cc)
        acc += Vs[cc] * ow[(size_t)(c0 + cc) * 768 + t];
    opart[((size_t)cs * 32 + b) * 768 + t] = acc;
}

// attn finish: y = latents+emb+ob+sum_cs opart; RMSNorm -> lat2
__global__ void attnfin_k(const float* __restrict__ opart, const float* __restrict__ ob,
                          const float* __restrict__ latents, const float* __restrict__ emb,
                          const float* __restrict__ nw, float* __restrict__ lat2) {
    int b = blockIdx.x, t = threadIdx.x;   // 768
    float y = latents[t] + emb[b * 768 + t] + ob[t];
    #pragma unroll
    for (int cs = 0; cs < 8; ++cs) y += opart[((size_t)cs * 32 + b) * 768 + t];
    float s = y * y;
    for (int off = 32; off > 0; off >>= 1) s += __shfl_down(s, off);
    __shared__ float red[12];
    if ((t & 63) == 0) red[t >> 6] = s;
    __syncthreads();
    float tot = 0.f;
    #pragma unroll
    for (int w = 0; w < 12; ++w) tot += red[w];
    float rstd = rsqrtf(tot / 768.0f + EPSV);
    lat2[b * 768 + t] = y * rstd * nw[t];
}

// GLU pre-activation partials, 8 batches per block:
__global__ void glu_k(const float* __restrict__ lat2, const float* __restrict__ gw,
                      const float* __restrict__ gb, float* __restrict__ hbuf) {
    int jt = blockIdx.x, bg = blockIdx.y, cs = blockIdx.z, t = threadIdx.x;
    int j = jt * 256 + t;   // < 3072
    int b0 = bg * 8, c0 = cs * 128;
    float accP[8] = {}, accG[8] = {};
    if (cs == 0) {
        float bp = gb[j], bgv = gb[j + 3072];
        #pragma unroll
        for (int bb = 0; bb < 8; ++bb) { accP[bb] = bp; accG[bb] = bgv; }
    }
    const float* __restrict__ l2 = &lat2[(size_t)b0 * 768 + c0];
    for (int c = 0; c < 128; ++c) {
        float wp = gw[(size_t)(c0 + c) * 6144 + j];
        float wg = gw[(size_t)(c0 + c) * 6144 + 3072 + j];
        #pragma unroll
        for (int bb = 0; bb < 8; ++bb) {
            float lv = l2[bb * 768 + c];         // uniform -> s_load
            accP[bb] += lv * wp;
            accG[bb] += lv * wg;
        }
    }
    #pragma unroll
    for (int bb = 0; bb < 8; ++bb) {
        atomicAdd(&hbuf[(size_t)(b0 + bb) * 6144 + j],        accP[bb]);
        atomicAdd(&hbuf[(size_t)(b0 + bb) * 6144 + 3072 + j], accG[bb]);
    }
}

// silu finish: mlpin[b][j] = P * silu(G)
__global__ void gfin_k(const float* __restrict__ hbuf, float* __restrict__ mlpin) {
    int idx = blockIdx.x * 256 + threadIdx.x;   // < 98304
    int b = idx / 3072, j = idx % 3072;
    float P = hbuf[(size_t)b * 6144 + j];
    float G = hbuf[(size_t)b * 6144 + 3072 + j];
    mlpin[idx] = P * (G / (1.0f + __expf(-G)));
}

// mlp[b,j] += mlp_in[b, i-chunk] @ mlp_out_w[i-chunk, j]  (+bias once; pre-zeroed)
__global__ void mlpout_k(const float* __restrict__ mlpin, const float* __restrict__ mw,
                         const float* __restrict__ mb, float* __restrict__ mlp) {
    int jt = blockIdx.x, bg = blockIdx.y, ic = blockIdx.z, t = threadIdx.x;
    int j = jt * 256 + t;   // < 768
    int i0 = ic * 192;
    const float* __restrict__ mi = &mlpin[(size_t)(bg * 4) * 3072 + i0];
    float acc[4] = {0.f, 0.f, 0.f, 0.f};
    for (int i = 0; i < 192; ++i) {
        float w = mw[(size_t)(i0 + i) * 768 + j];
        #pragma unroll
        for (int bb = 0; bb < 4; ++bb)
            acc[bb] += mi[bb * 3072 + i] * w;    // uniform -> s_load
    }
    float bias = (ic == 0) ? mb[j] : 0.f;
    #pragma unroll
    for (int bb = 0; bb < 4; ++bb)
        atomicAdd(&mlp[(bg * 4 + bb) * 768 + j], acc[bb] + bias);
}

// final residual + RMSNorm -> out
__global__ void fnorm_k(const float* __restrict__ lat2, const float* __restrict__ mlp,
                        const float* __restrict__ nw, float* __restrict__ out) {
    int b = blockIdx.x, t = threadIdx.x;   // block = 768
    float y = lat2[b * 768 + t] + mlp[b * 768 + t];
    float s = y * y;
    for (int off = 32; off > 0; off >>= 1) s += __shfl_down(s, off);
    __shared__ float red[12];
    if ((t & 63) == 0) red[t >> 6] = s;
    __syncthreads();
    float tot = 0.f;
    #pragma unroll
    for (int w = 0; w < 12; ++w) tot += red[w];
    float rstd = rsqrtf(tot / 768.0f + EPSV);
    out[b * 768 + t] = y * rstd * nw[t];
}

extern "C" void kernel_launch(void* const* d_in, const int* in_sizes, int n_in,
                              void* d_out, int out_size, void* d_ws, size_t ws_size,
                              hipStream_t stream) {
    const float* x       = (const float*)d_in[0];
    const float* emb     = (const float*)d_in[1];
    const float* latents = (const float*)d_in[2];
    const float* proj_w  = (const float*)d_in[3];
    const float* proj_b  = (const float*)d_in[4];
    const float* q_w     = (const float*)d_in[5];
    const float* kv_w    = (const float*)d_in[6];
    const float* ao_w    = (const float*)d_in[7];
    const float* ao_b    = (const float*)d_in[8];
    const float* anw     = (const float*)d_in[9];
    const float* mnw     = (const float*)d_in[10];
    const float* glu_w   = (const float*)d_in[11];
    const float* glu_b   = (const float*)d_in[12];
    const float* mo_w    = (const float*)d_in[13];
    const float* mo_b    = (const float*)d_in[14];

    float* ws    = (float*)d_ws;
    float* Wf    = ws + OFF_WF;
    float* wqT   = ws + OFF_WQ;
    float* Sp    = ws + OFF_S;
    float* ppart = ws + OFF_PPART;
    float* mlp   = ws + OFF_MLP;
    float* kvb   = ws + OFF_KVB;
    float* hbuf  = ws + OFF_HBUF;
    float* q     = ws + OFF_Q;
    float* vpart = ws + OFF_VPART;
    float* opart = ws + OFF_OPART;
    float* lat2  = ws + OFF_LAT2;
    float* mlpin = ws + OFF_MLPIN;

    // zero mlp + kvb + hbuf + q (contiguous) for atomic accumulation
    hipMemsetAsync(ws + ZERO_START, 0, (size_t)ZERO_FLOATS * sizeof(float), stream);

    wf_gemm<<<dim3(24, 24), 256, 0, stream>>>(proj_w, kv_w, Wf);
    kvbias_k<<<dim3(3, 16), 256, 0, stream>>>(proj_b, kv_w, kvb);
    q_k<<<dim3(3, 32, 4), 256, 0, stream>>>(latents, emb, q_w, q);
    wq_k<<<dim3(24, 16), 256, 0, stream>>>(Wf, q, wqT);

    scores_k<<<dim3(16, 2, 32), 256, 0, stream>>>(x, wqT, Sp);
    softmax_k<<<dim3(768), 256, 0, stream>>>(Sp);
    pooled_k<<<dim3(16, 32), 192, 0, stream>>>(x, Sp, ppart);

    vals_k<<<dim3(32, 8), 768, 0, stream>>>(ppart, Wf, vpart);
    oproj_k<<<dim3(32, 8), 768, 0, stream>>>(vpart, kvb, ao_w, opart);
    attnfin_k<<<dim3(32), 768, 0, stream>>>(opart, ao_b, latents, emb, anw, lat2);

    glu_k<<<dim3(12, 4, 6), 256, 0, stream>>>(lat2, glu_w, glu_b, hbuf);
    gfin_k<<<dim3(384), 256, 0, stream>>>(hbuf, mlpin);
    mlpout_k<<<dim3(3, 8, 16), 256, 0, stream>>>(mlpin, mo_w, mo_b, mlp);
    fnorm_k<<<dim3(32), 768, 0, stream>>>(lat2, mlp, mnw, (float*)d_out);
}

// Round 16
// 396.694 us; speedup vs baseline: 3.1830x; 1.0024x over previous
//
#include <hip/hip_runtime.h>
#include <math.h>

#define BB 32
#define NN 4096
#define CC 768
#define HH 24
#define HID 3072
#define N2 1536   // 2*C
#define EPSV 1e-6f
#define SCALE 0.17677669529663687f  // 1/sqrt(32)

#define SLICE_S  ((size_t)BB*HH*NN)           // 3,145,728 (one cs score slice)

// workspace offsets (in floats). MLP/KVB/HBUF/Q contiguous -> single memset.
#define OFF_WF     0                          // 1,179,648
#define OFF_WQ     (OFF_WF   + CC*N2)         // wqT: [b][c][24]
#define OFF_S      (OFF_WQ   + BB*HH*CC)      // Spart: [2][b][h][n]; slice0 = final S
#define OFF_PPART  (OFF_S    + 2*BB*HH*NN)    // [16][b][h][c]
#define OFF_MLP    (OFF_PPART+ 16*BB*HH*CC)   // zeroed
#define OFF_KVB    (OFF_MLP  + BB*CC)         // zeroed
#define OFF_HBUF   (OFF_KVB  + N2)            // zeroed, [32][6144]
#define OFF_Q      (OFF_HBUF + BB*2*HID)      // zeroed (atomic accum)
#define OFF_VPART  (OFF_Q    + BB*CC)         // [8][b][768]
#define OFF_OPART  (OFF_VPART+ 8*BB*CC)       // [8][b][768]
#define OFF_LAT2   (OFF_OPART+ 8*BB*CC)
#define ZERO_START OFF_MLP
#define ZERO_FLOATS (BB*CC + N2 + BB*2*HID + BB*CC)

// ---------------------------------------------------------------------------
// Wf = proj_w (768x768) @ kv_w (768x1536).  BM=32 BN=64 BK=32, 2x4 micro-tile.
__global__ void wf_gemm(const float* __restrict__ A, const float* __restrict__ Bm,
                        float* __restrict__ Wf) {
    __shared__ float As[32][34];   // [kk][m], transposed
    __shared__ float Bs[32][68];   // [kk][n]
    int t = threadIdx.x;
    int tx = t & 15, ty = t >> 4;
    int n0 = blockIdx.x * 64, m0 = blockIdx.y * 32;
    int ar = t >> 3, ak4 = t & 7;
    int bk = t >> 4, bn4 = t & 15;
    const float* Ap  = &A[(size_t)(m0 + ar) * 768 + ak4 * 4];
    const float* Bp0 = &Bm[(size_t)bk * 1536 + n0 + bn4 * 4];
    const float* Bp1 = &Bm[(size_t)(bk + 16) * 1536 + n0 + bn4 * 4];
    float4 a_reg  = *(const float4*)Ap;
    float4 b_reg0 = *(const float4*)Bp0;
    float4 b_reg1 = *(const float4*)Bp1;
    float acc[2][4] = {};
    for (int kt = 0; kt < 24; ++kt) {
        __syncthreads();
        As[ak4 * 4 + 0][ar] = a_reg.x;
        As[ak4 * 4 + 1][ar] = a_reg.y;
        As[ak4 * 4 + 2][ar] = a_reg.z;
        As[ak4 * 4 + 3][ar] = a_reg.w;
        *(float4*)&Bs[bk][bn4 * 4]      = b_reg0;
        *(float4*)&Bs[bk + 16][bn4 * 4] = b_reg1;
        __syncthreads();
        if (kt < 23) {
            int k0 = (kt + 1) * 32;
            a_reg  = *(const float4*)(Ap + k0);
            b_reg0 = *(const float4*)(Bp0 + (size_t)k0 * 1536);
            b_reg1 = *(const float4*)(Bp1 + (size_t)k0 * 1536);
        }
        #pragma unroll
        for (int kk = 0; kk < 32; ++kk) {
            float a0 = As[kk][ty * 2], a1 = As[kk][ty * 2 + 1];
            float4 bv = *(const float4*)&Bs[kk][tx * 4];
            acc[0][0] += a0 * bv.x; acc[0][1] += a0 * bv.y;
            acc[0][2] += a0 * bv.z; acc[0][3] += a0 * bv.w;
            acc[1][0] += a1 * bv.x; acc[1][1] += a1 * bv.y;
            acc[1][2] += a1 * bv.z; acc[1][3] += a1 * bv.w;
        }
    }
    #pragma unroll
    for (int i = 0; i < 2; ++i) {
        int m = m0 + ty * 2 + i;
        *(float4*)&Wf[(size_t)m * 1536 + n0 + tx * 4] =
            make_float4(acc[i][0], acc[i][1], acc[i][2], acc[i][3]);
    }
}

// V-half bias only (K bias cancels in softmax). i-split x16 (48 blocks).
__global__ void kvbias_k(const float* __restrict__ pb, const float* __restrict__ kvw,
                         float* __restrict__ kvb) {
    int j = 768 + blockIdx.x * 256 + threadIdx.x;
    int i0 = blockIdx.y * 48;
    float acc = 0.f;
    for (int i = i0; i < i0 + 48; ++i) acc += pb[i] * kvw[(size_t)i * 1536 + j];
    atomicAdd(&kvb[j], acc);
}

// q[b,j] += (latents + emb[b])[c-chunk] @ q_w[c-chunk, j]   (q pre-zeroed; c-split x4)
__global__ void q_k(const float* __restrict__ latents, const float* __restrict__ emb,
                    const float* __restrict__ qw, float* __restrict__ q) {
    __shared__ float Ls[192];
    int b = blockIdx.y, cs = blockIdx.z, t = threadIdx.x;
    int c0 = cs * 192;
    if (t < 192) Ls[t] = latents[c0 + t] + emb[b * 768 + c0 + t];
    __syncthreads();
    int j = blockIdx.x * 256 + t;
    float acc = 0.f;
    for (int c = 0; c < 192; ++c) acc += Ls[c] * qw[(size_t)(c0 + c) * 768 + j];
    atomicAdd(&q[b * 768 + j], acc);
}

// wqT[b,c,h] = scale * sum_d Wf[c, h*32+d] * q[b,h*32+d]   (2 batches/block)
__global__ void wq_k(const float* __restrict__ Wf, const float* __restrict__ q,
                     float* __restrict__ wqT) {
    int h = blockIdx.x, b0 = blockIdx.y * 2, t = threadIdx.x;
    __shared__ float qh[2][32];
    if (t < 64) qh[t >> 5][t & 31] = q[(b0 + (t >> 5)) * 768 + h * 32 + (t & 31)];
    __syncthreads();
    for (int c = t; c < 768; c += 256) {
        const float4* wrow = (const float4*)&Wf[(size_t)c * 1536 + h * 32];
        float a0 = 0.f, a1 = 0.f;
        #pragma unroll
        for (int d4 = 0; d4 < 8; ++d4) {
            float4 w = wrow[d4];
            a0 += w.x * qh[0][4*d4] + w.y * qh[0][4*d4+1] + w.z * qh[0][4*d4+2] + w.w * qh[0][4*d4+3];
            a1 += w.x * qh[1][4*d4] + w.y * qh[1][4*d4+1] + w.z * qh[1][4*d4+2] + w.w * qh[1][4*d4+3];
        }
        wqT[((size_t)(b0 + 0) * 768 + c) * 24 + h] = SCALE * a0;
        wqT[((size_t)(b0 + 1) * 768 + c) * 24 + h] = SCALE * a1;
    }
}

// Spart[cs][b][h][n] = x[b,n,cs-range] . wqT[b,cs-range,h]    (pass 1 over x)
// Wave-private LDS staging (NO barriers). PROVEN — do not touch.
__global__ void scores_k(const float* __restrict__ x, const float* __restrict__ wqT,
                         float* __restrict__ Spart) {
    __shared__ float Xs[4][64][33];
    int b = blockIdx.z, cs = blockIdx.y;
    int t = threadIdx.x;
    int w = t >> 6, lane = t & 63;
    int n0 = blockIdx.x * 256 + w * 64;
    int sr = lane >> 3, sc = (lane & 7) * 4;   // staging: 8 rows x 32 floats
    const float* __restrict__ xbase = &x[((size_t)b * 4096 + n0) * 768 + cs * 384];
    const float* __restrict__ wb = &wqT[((size_t)b * 768 + cs * 384) * 24];
    float (*Xw)[33] = Xs[w];
    float acc[24];
    #pragma unroll
    for (int h = 0; h < 24; ++h) acc[h] = 0.f;
    float4 pf[8];
    #pragma unroll
    for (int it = 0; it < 8; ++it)
        pf[it] = *(const float4*)&xbase[(size_t)(sr + 8 * it) * 768 + sc];
    for (int ck = 0; ck < 12; ++ck) {
        #pragma unroll
        for (int it = 0; it < 8; ++it) {
            int r = sr + 8 * it;
            Xw[r][sc + 0] = pf[it].x; Xw[r][sc + 1] = pf[it].y;
            Xw[r][sc + 2] = pf[it].z; Xw[r][sc + 3] = pf[it].w;
        }
        if (ck < 11) {
            #pragma unroll
            for (int it = 0; it < 8; ++it)
                pf[it] = *(const float4*)&xbase[(size_t)(sr + 8 * it) * 768 + (ck + 1) * 32 + sc];
        }
        const float* __restrict__ wc = &wb[ck * 32 * 24];
        #pragma unroll
        for (int cc = 0; cc < 32; ++cc) {
            float xv = Xw[lane][cc];
            #pragma unroll
            for (int h = 0; h < 24; ++h)
                acc[h] += xv * wc[cc * 24 + h];          // uniform -> s_load
        }
    }
    int n = n0 + lane;
    #pragma unroll
    for (int h = 0; h < 24; ++h)
        Spart[((size_t)(cs * 32 + b) * 24 + h) * 4096 + n] = acc[h];
}

// softmax over n: S = softmax(p0 + p1); writes into slice 0 (final S)
__global__ void softmax_k(float* __restrict__ Sp) {
    int row = blockIdx.x;            // b*24 + h
    int t = threadIdx.x;
    size_t base = (size_t)row * 4096;
    float v[16];
    float m = -1e30f;
    #pragma unroll
    for (int i = 0; i < 16; ++i) {
        int idx = t + 256 * i;
        v[i] = Sp[base + idx] + Sp[SLICE_S + base + idx];
        m = fmaxf(m, v[i]);
    }
    __shared__ float redm[4];
    for (int off = 32; off > 0; off >>= 1) m = fmaxf(m, __shfl_down(m, off));
    if ((t & 63) == 0) redm[t >> 6] = m;
    __syncthreads();
    m = fmaxf(fmaxf(redm[0], redm[1]), fmaxf(redm[2], redm[3]));
    float s = 0.f;
    #pragma unroll
    for (int i = 0; i < 16; ++i) { v[i] = __expf(v[i] - m); s += v[i]; }
    __shared__ float reds[4];
    for (int off = 32; off > 0; off >>= 1) s += __shfl_down(s, off);
    if ((t & 63) == 0) reds[t >> 6] = s;
    __syncthreads();
    s = reds[0] + reds[1] + reds[2] + reds[3];
    float inv = 1.0f / s;
    #pragma unroll
    for (int i = 0; i < 16; ++i) Sp[base + t + 256 * i] = v[i] * inv;
}

// ppart[nt][b][h][c] = sum_{n in 256-chunk} S[b,h,n] * x[b,n,c]  (pass 2 over x)
// PROVEN — do not touch.
__global__ void pooled_k(const float* __restrict__ x, const float* __restrict__ S,
                         float* __restrict__ ppart) {
    int nt = blockIdx.x, b = blockIdx.y;
    int t = threadIdx.x;          // 0..191
    int c = t * 4;
    int n0 = nt * 256;
    const float* __restrict__ Sb = &S[(size_t)b * 24 * 4096 + n0];
    const float* __restrict__ xb = &x[((size_t)b * 4096 + n0) * 768 + c];
    float ax[24], ay[24], az[24], aw[24];
    #pragma unroll
    for (int h = 0; h < 24; ++h) { ax[h]=0.f; ay[h]=0.f; az[h]=0.f; aw[h]=0.f; }
    #pragma unroll 4
    for (int i = 0; i < 256; ++i) {
        float4 xv = *(const float4*)&xb[(size_t)i * 768];
        #pragma unroll
        for (int h = 0; h < 24; ++h) {
            float s = Sb[h * 4096 + i];          // uniform -> s_load
            ax[h] += s * xv.x; ay[h] += s * xv.y;
            az[h] += s * xv.z; aw[h] += s * xv.w;
        }
    }
    float* dst = &ppart[(size_t)(nt * 32 + b) * 24 * 768];
    #pragma unroll
    for (int h = 0; h < 24; ++h)
        *(float4*)&dst[h * 768 + c] = make_float4(ax[h], ay[h], az[h], aw[h]);
}

// vpart[cs][b][j] = sum_{c in 96-range} (sum_nt ppart[nt][b][h(j)][c]) * Wf[c,768+j]
__global__ void vals_k(const float* __restrict__ ppart, const float* __restrict__ Wf,
                       float* __restrict__ vpart) {
    __shared__ float Ls[24][96];
    int b = blockIdx.x, cs = blockIdx.y, t = threadIdx.x;   // block = 768
    int c0 = cs * 96;
    for (int idx = t; idx < 24 * 96; idx += 768) {
        int hh = idx / 96, cc = idx % 96;
        size_t base = (size_t)b * 24 * 768 + hh * 768 + c0 + cc;
        float s = 0.f;
        #pragma unroll 4
        for (int sl = 0; sl < 16; ++sl)
            s += ppart[(size_t)sl * 32 * 24 * 768 + base];
        Ls[hh][cc] = s;
    }
    __syncthreads();
    int h = t >> 5;
    float acc = 0.f;
    for (int cc = 0; cc < 96; ++cc)
        acc += Ls[h][cc] * Wf[(size_t)(c0 + cc) * 1536 + 768 + t];
    vpart[((size_t)cs * 32 + b) * 768 + t] = acc;
}

// opart[cs][b][j] = sum_{c in 96-range} vals[b,c] * ow[c,j]
__global__ void oproj_k(const float* __restrict__ vpart, const float* __restrict__ kvb,
                        const float* __restrict__ ow, float* __restrict__ opart) {
    __shared__ float Vs[96];
    int b = blockIdx.x, cs = blockIdx.y, t = threadIdx.x;   // block = 768
    int c0 = cs * 96;
    if (t < 96) {
        float v = kvb[768 + c0 + t];
        #pragma unroll
        for (int s2 = 0; s2 < 8; ++s2) v += vpart[((size_t)s2 * 32 + b) * 768 + c0 + t];
        Vs[t] = v;
    }
    __syncthreads();
    float acc = 0.f;
    for (int cc = 0; cc < 96; ++cc)
        acc += Vs[cc] * ow[(size_t)(c0 + cc) * 768 + t];
    opart[((size_t)cs * 32 + b) * 768 + t] = acc;
}

// attn finish: y = latents+emb+ob+sum_cs opart; RMSNorm -> lat2
__global__ void attnfin_k(const float* __restrict__ opart, const float* __restrict__ ob,
                          const float* __restrict__ latents, const float* __restrict__ emb,
                          const float* __restrict__ nw, float* __restrict__ lat2) {
    int b = blockIdx.x, t = threadIdx.x;   // 768
    float y = latents[t] + emb[b * 768 + t] + ob[t];
    #pragma unroll
    for (int cs = 0; cs < 8; ++cs) y += opart[((size_t)cs * 32 + b) * 768 + t];
    float s = y * y;
    for (int off = 32; off > 0; off >>= 1) s += __shfl_down(s, off);
    __shared__ float red[12];
    if ((t & 63) == 0) red[t >> 6] = s;
    __syncthreads();
    float tot = 0.f;
    #pragma unroll
    for (int w = 0; w < 12; ++w) tot += red[w];
    float rstd = rsqrtf(tot / 768.0f + EPSV);
    lat2[b * 768 + t] = y * rstd * nw[t];
}

// GLU pre-activation partials, 16 batches per block (gw redundancy 4x -> 2x):
__global__ void glu_k(const float* __restrict__ lat2, const float* __restrict__ gw,
                      const float* __restrict__ gb, float* __restrict__ hbuf) {
    int jt = blockIdx.x, bg = blockIdx.y, cs = blockIdx.z, t = threadIdx.x;
    int j = jt * 256 + t;   // < 3072
    int b0 = bg * 16, c0 = cs * 64;
    float accP[16] = {}, accG[16] = {};
    if (cs == 0) {
        float bp = gb[j], bgv = gb[j + 3072];
        #pragma unroll
        for (int bb = 0; bb < 16; ++bb) { accP[bb] = bp; accG[bb] = bgv; }
    }
    const float* __restrict__ l2 = &lat2[(size_t)b0 * 768 + c0];
    for (int c = 0; c < 64; ++c) {
        float wp = gw[(size_t)(c0 + c) * 6144 + j];
        float wg = gw[(size_t)(c0 + c) * 6144 + 3072 + j];
        #pragma unroll
        for (int bb = 0; bb < 16; ++bb) {
            float lv = l2[bb * 768 + c];         // uniform -> s_load
            accP[bb] += lv * wp;
            accG[bb] += lv * wg;
        }
    }
    #pragma unroll
    for (int bb = 0; bb < 16; ++bb) {
        atomicAdd(&hbuf[(size_t)(b0 + bb) * 6144 + j],        accP[bb]);
        atomicAdd(&hbuf[(size_t)(b0 + bb) * 6144 + 3072 + j], accG[bb]);
    }
}

// mlp[b,j] += silu-activated hbuf tile @ mlp_out_w[i-chunk, j]  (gfin fused:
// silu computed cooperatively into LDS, then same-address broadcasts)
__global__ void mlpout_k(const float* __restrict__ hbuf, const float* __restrict__ mw,
                         const float* __restrict__ mb, float* __restrict__ mlp) {
    __shared__ float Ms[4][192];
    int jt = blockIdx.x, bg = blockIdx.y, ic = blockIdx.z, t = threadIdx.x;
    int j = jt * 256 + t;   // < 768
    int i0 = ic * 192;
    int b0 = bg * 4;
    for (int idx = t; idx < 4 * 192; idx += 256) {
        int bb = idx / 192, ii = idx % 192;
        float P = hbuf[(size_t)(b0 + bb) * 6144 + i0 + ii];
        float G = hbuf[(size_t)(b0 + bb) * 6144 + 3072 + i0 + ii];
        Ms[bb][ii] = P * (G / (1.0f + __expf(-G)));
    }
    __syncthreads();
    float acc[4] = {0.f, 0.f, 0.f, 0.f};
    for (int i = 0; i < 192; ++i) {
        float w = mw[(size_t)(i0 + i) * 768 + j];
        #pragma unroll
        for (int bb = 0; bb < 4; ++bb)
            acc[bb] += Ms[bb][i] * w;            // same-address broadcast: free
    }
    float bias = (ic == 0) ? mb[j] : 0.f;
    #pragma unroll
    for (int bb = 0; bb < 4; ++bb)
        atomicAdd(&mlp[(b0 + bb) * 768 + j], acc[bb] + bias);
}

// final residual + RMSNorm -> out
__global__ void fnorm_k(const float* __restrict__ lat2, const float* __restrict__ mlp,
                        const float* __restrict__ nw, float* __restrict__ out) {
    int b = blockIdx.x, t = threadIdx.x;   // block = 768
    float y = lat2[b * 768 + t] + mlp[b * 768 + t];
    float s = y * y;
    for (int off = 32; off > 0; off >>= 1) s += __shfl_down(s, off);
    __shared__ float red[12];
    if ((t & 63) == 0) red[t >> 6] = s;
    __syncthreads();
    float tot = 0.f;
    #pragma unroll
    for (int w = 0; w < 12; ++w) tot += red[w];
    float rstd = rsqrtf(tot / 768.0f + EPSV);
    out[b * 768 + t] = y * rstd * nw[t];
}

extern "C" void kernel_launch(void* const* d_in, const int* in_sizes, int n_in,
                              void* d_out, int out_size, void* d_ws, size_t ws_size,
                              hipStream_t stream) {
    const float* x       = (const float*)d_in[0];
    const float* emb     = (const float*)d_in[1];
    const float* latents = (const float*)d_in[2];
    const float* proj_w  = (const float*)d_in[3];
    const float* proj_b  = (const float*)d_in[4];
    const float* q_w     = (const float*)d_in[5];
    const float* kv_w    = (const float*)d_in[6];
    const float* ao_w    = (const float*)d_in[7];
    const float* ao_b    = (const float*)d_in[8];
    const float* anw     = (const float*)d_in[9];
    const float* mnw     = (const float*)d_in[10];
    const float* glu_w   = (const float*)d_in[11];
    const float* glu_b   = (const float*)d_in[12];
    const float* mo_w    = (const float*)d_in[13];
    const float* mo_b    = (const float*)d_in[14];

    float* ws    = (float*)d_ws;
    float* Wf    = ws + OFF_WF;
    float* wqT   = ws + OFF_WQ;
    float* Sp    = ws + OFF_S;
    float* ppart = ws + OFF_PPART;
    float* mlp   = ws + OFF_MLP;
    float* kvb   = ws + OFF_KVB;
    float* hbuf  = ws + OFF_HBUF;
    float* q     = ws + OFF_Q;
    float* vpart = ws + OFF_VPART;
    float* opart = ws + OFF_OPART;
    float* lat2  = ws + OFF_LAT2;

    // zero mlp + kvb + hbuf + q (contiguous) for atomic accumulation
    hipMemsetAsync(ws + ZERO_START, 0, (size_t)ZERO_FLOATS * sizeof(float), stream);

    wf_gemm<<<dim3(24, 24), 256, 0, stream>>>(proj_w, kv_w, Wf);
    kvbias_k<<<dim3(3, 16), 256, 0, stream>>>(proj_b, kv_w, kvb);
    q_k<<<dim3(3, 32, 4), 256, 0, stream>>>(latents, emb, q_w, q);
    wq_k<<<dim3(24, 16), 256, 0, stream>>>(Wf, q, wqT);

    scores_k<<<dim3(16, 2, 32), 256, 0, stream>>>(x, wqT, Sp);
    softmax_k<<<dim3(768), 256, 0, stream>>>(Sp);
    pooled_k<<<dim3(16, 32), 192, 0, stream>>>(x, Sp, ppart);

    vals_k<<<dim3(32, 8), 768, 0, stream>>>(ppart, Wf, vpart);
    oproj_k<<<dim3(32, 8), 768, 0, stream>>>(vpart, kvb, ao_w, opart);
    attnfin_k<<<dim3(32), 768, 0, stream>>>(opart, ao_b, latents, emb, anw, lat2);

    glu_k<<<dim3(12, 2, 12), 256, 0, stream>>>(lat2, glu_w, glu_b, hbuf);
    mlpout_k<<<dim3(3, 8, 16), 256, 0, stream>>>(hbuf, mo_w, mo_b, mlp);
    fnorm_k<<<dim3(32), 768, 0, stream>>>(lat2, mlp, mnw, (float*)d_out);
}